// Round 4
// baseline (4083.525 us; speedup 1.0000x reference)
//
#include <hip/hip_runtime.h>
#include <hip/hip_bf16.h>

#define N_VOX 150000
#define CH 32
#define KVOL 27
#define NCLS 20
#define TOT (KVOL * N_VOX)          // 4,050,000
#define MPAD 150016
#define NPART 586                   // MPAD / 256
#define BCAP 576                    // per-wave bucket capacity (mean 432, +6.9 sigma)
#define WG_U32 (KVOL * 512)         // 13824 u32 per prepped weight set

typedef __attribute__((ext_vector_type(4))) float f32x4;
typedef __attribute__((ext_vector_type(8))) short short8;

#define WSYNC() asm volatile("s_waitcnt lgkmcnt(0)" ::: "memory")

__device__ __forceinline__ unsigned int pk_bf16(float a, float b) {
  unsigned int ua = __float_as_uint(a), ub = __float_as_uint(b);
  ua = ua + 0x7FFFu + ((ua >> 16) & 1u);     // RNE
  ub = ub + 0x7FFFu + ((ub >> 16) & 1u);
  return (ub & 0xFFFF0000u) | (ua >> 16);
}
__device__ __forceinline__ float bf_lo(unsigned int u) { return __uint_as_float(u << 16); }
__device__ __forceinline__ float bf_hi(unsigned int u) { return __uint_as_float(u & 0xFFFF0000u); }

// ============================ rulebook inversion ============================

__global__ __launch_bounds__(256) void k_hist(const int* __restrict__ sidx,
                                              int* __restrict__ cnt) {
  int e = blockIdx.x * 256 + threadIdx.x;
  if (e < TOT) atomicAdd(&cnt[sidx[e]], 1);
}

__global__ __launch_bounds__(256) void k_scan1(const int* __restrict__ cnt,
                                               int* __restrict__ tmp,
                                               int* __restrict__ part) {
  __shared__ int sb[256];
  int t = threadIdx.x;
  int gt = blockIdx.x * 256 + t;
  int v = cnt[gt];
  sb[t] = v;
  __syncthreads();
  for (int s = 1; s < 256; s <<= 1) {
    int a = (t >= s) ? sb[t - s] : 0;
    __syncthreads();
    sb[t] += a;
    __syncthreads();
  }
  tmp[gt] = sb[t] - v;
  if (t == 255) part[blockIdx.x] = sb[t];
}

__global__ __launch_bounds__(1024) void k_scan2(int* __restrict__ part) {
  __shared__ int sb[1024];
  int t = threadIdx.x;
  int v = (t < NPART) ? part[t] : 0;
  sb[t] = v;
  __syncthreads();
  for (int s = 1; s < 1024; s <<= 1) {
    int a = (t >= s) ? sb[t - s] : 0;
    __syncthreads();
    sb[t] += a;
    __syncthreads();
  }
  if (t < NPART) part[t] = sb[t] - v;
}

__global__ __launch_bounds__(256) void k_scan3(const int* __restrict__ tmp,
                                               const int* __restrict__ part,
                                               int* __restrict__ off) {
  int gt = blockIdx.x * 256 + threadIdx.x;
  off[gt] = tmp[gt] + part[blockIdx.x];
}

__global__ __launch_bounds__(256) void k_fill(const int* __restrict__ gidx,
                                              const int* __restrict__ sidx,
                                              const int* __restrict__ off,
                                              int* __restrict__ cur,
                                              int* __restrict__ pl) {
  int e = blockIdx.x * 256 + threadIdx.x;
  if (e >= TOT) return;
  int k = e / N_VOX;
  int s = sidx[e];
  int pos = atomicAdd(&cur[s], 1);
  pl[off[s] + pos] = (gidx[e] << 5) | k;
}

// ============================ weight prep (f32 -> B-frag bf16) ==============
__global__ __launch_bounds__(256) void k_wprep(const float* __restrict__ W,
                                               unsigned int* __restrict__ out) {
  int i = blockIdx.x * 256 + threadIdx.x;
  if (i >= WG_U32) return;
  int k = i >> 9, r = i & 511;
  int h = r >> 8, l = (r >> 2) & 63, w = r & 3;
  int ci0 = ((l >> 4) << 3) + (w << 1);
  int co = (l & 15) + (h << 4);
  const float* wk = W + k * 1024;
  out[i] = pk_bf16(wk[ci0 * 32 + co], wk[(ci0 + 1) * 32 + co]);
}

// ============================ f32 -> bf16 activation convert ================
__global__ __launch_bounds__(256) void k_tobf(const float4* __restrict__ in4,
                                              uint4* __restrict__ out4) {
  int i = blockIdx.x * 256 + threadIdx.x;
  if (i >= (N_VOX * CH) / 8) return;   // 600000
  float4 f0 = in4[i * 2], f1 = in4[i * 2 + 1];
  uint4 o;
  o.x = pk_bf16(f0.x, f0.y); o.y = pk_bf16(f0.z, f0.w);
  o.z = pk_bf16(f1.x, f1.y); o.w = pk_bf16(f1.z, f1.w);
  out4[i] = o;
}

// ============================ MFMA conv kernel ==============================
// Block = 512 thr = 8 waves, 1 block/CU (110 KB LDS). Each wave owns 16 rows:
// bucket CSR entries by k -> flattened chunk list -> 2-deep software-pipelined
// gather / double-buffered A-tile / MFMA / swizzled LDS ds_add scatter.
// No cross-wave syncs after the W stage. No global atomics.

// compute gather address (in uint4 units) for this lane's piece of chunk d
#define ADDR(d, aout) { aout = -1; \
  if ((d) >= 0) { \
    int kA_ = (d) >> 10, cbA_ = (d) & 1023; \
    int keA_ = kep[kA_]; if (keA_ > BCAP) keA_ = BCAP; \
    int slA_ = cbA_ + e_; \
    if (slA_ < keA_) aout = (int)(bkt[slA_] >> 4) * 4 + b_; } }

#define SCAT(rr) { \
  int s2_ = cb_ + e0 + (rr); \
  if (s2_ < ke2_) { \
    int lr_ = (int)(bkt[s2_] & 15u); \
    int sw_ = co ^ ((lr_ & 1) << 4); \
    atomicAdd(&acc_s[lr_ * 32 + sw_], c0_[rr]); \
    atomicAdd(&acc_s[lr_ * 32 + (sw_ ^ 16)], c1_[rr]); \
  } }

#define CONSUME(d, P, BUFOFS) if ((d) >= 0) { \
  int k2_ = (d) >> 10, cb_ = (d) & 1023; \
  int ke2_ = kep[k2_]; if (ke2_ > BCAP) ke2_ = BCAP; \
  A4[(BUFOFS) + (e_ << 2) + (b_ ^ (e_ & 3))] = (P); \
  WSYNC(); \
  uint4 av_ = A4[(BUFOFS) + (am << 2) + ab]; \
  uint4 bv0_ = sW4[k2_ * 128 + l]; \
  uint4 bv1_ = sW4[k2_ * 128 + 64 + l]; \
  union { uint4 u; short8 s; } ua_, ub0_, ub1_; \
  ua_.u = av_; ub0_.u = bv0_; ub1_.u = bv1_; \
  f32x4 c0_ = __builtin_amdgcn_mfma_f32_16x16x32_bf16(ua_.s, ub0_.s, cz, 0, 0, 0); \
  f32x4 c1_ = __builtin_amdgcn_mfma_f32_16x16x32_bf16(ua_.s, ub1_.s, cz, 0, 0, 0); \
  SCAT(0) SCAT(1) SCAT(2) SCAT(3) }

__global__ __launch_bounds__(512, 1) void k_conv(
    const uint4* __restrict__ src4, unsigned int* __restrict__ dst,
    const int* __restrict__ off, const int* __restrict__ pl,
    const uint4* __restrict__ Wg4, const float* __restrict__ bias) {
  __shared__ uint4 sW4[KVOL * 128];              // 55296 B, B-frag order
  __shared__ float sAcc[8][512];                 // 16 x 32 f32/wave, XOR-swizzled
  __shared__ uint4 sA4[8][128];                  // double-buffered A-tile
  __shared__ unsigned int sBkt[8][BCAP];         // (gi<<4)|lrow
  __shared__ int sKb[8][32], sKe[8][32];         // per-k start / end(cursor)
  __shared__ int sChk[8][64];                    // counts, then chunk descs
  __shared__ int sNch[8];

  const int tid = threadIdx.x;
  for (int i = tid; i < KVOL * 128; i += 512) sW4[i] = Wg4[i];
  __syncthreads();

  const int wv = tid >> 6, l = tid & 63;
  const int r0 = (blockIdx.x * 8 + wv) * 16;

  float* acc_s = sAcc[wv];
  uint4* A4 = sA4[wv];
  unsigned int* bkt = sBkt[wv];
  int* kb = sKb[wv];
  int* kep = sKe[wv];
  int* chkp = sChk[wv];

  for (int i = l; i < 512; i += 64) acc_s[i] = 0.f;
  if (l < 32) chkp[l] = 0;                       // counts
  WSYNC();

  // ---- bucket by k (4 lanes per row) ----
  const int rr_ = l >> 2, jj = l & 3;
  const int row_g = r0 + rr_;
  int eb = 0, ee = 0;
  if (row_g < N_VOX) { eb = off[row_g]; ee = off[row_g + 1]; }

  for (int i = eb + jj; i < ee; i += 4) atomicAdd(&chkp[pl[i] & 31], 1);
  WSYNC();
  if (l == 0) {
    int s = 0;
    for (int k = 0; k < KVOL; k++) { kb[k] = s; kep[k] = s; s += chkp[k]; }
  }
  WSYNC();
  for (int i = eb + jj; i < ee; i += 4) {
    int p = pl[i];
    int pos = atomicAdd(&kep[p & 31], 1);        // kep becomes per-k end
    if (pos < BCAP) bkt[pos] = (unsigned int)((((unsigned int)p >> 5) << 4) | (unsigned int)rr_);
  }
  WSYNC();

  // ---- flatten chunk descriptor list ----
  if (l == 0) {
    int n = 0;
    for (int k = 0; k < KVOL; k++) {
      int b = kb[k], e = kep[k];
      if (e > BCAP) e = BCAP;
      for (int cb = b; cb < e; cb += 16) chkp[n++] = (k << 10) | cb;
    }
    sNch[wv] = n;
  }
  WSYNC();
  const int nch = sNch[wv];

  // ---- pipelined main loop ----
  const f32x4 cz = {0.f, 0.f, 0.f, 0.f};
  const uint4 z4 = {0u, 0u, 0u, 0u};
  const int e_ = l >> 2, b_ = l & 3;               // stage: 4 lanes per entry
  const int am = l & 15, ab = (l >> 4) ^ (l & 3);  // A-frag read (XOR swizzle)
  const int e0 = (l >> 4) << 2, co = l & 15;       // C scatter

  int d0 = (nch > 0) ? chkp[0] : -1;
  int d1 = (nch > 1) ? chkp[1] : -1;
  int a0, a1;
  ADDR(d0, a0);
  ADDR(d1, a1);
  uint4 P0 = (a0 >= 0) ? src4[a0] : z4;
  uint4 P1 = (a1 >= 0) ? src4[a1] : z4;

  for (int j = 0; j < nch; j += 2) {
    int d2 = (j + 2 < nch) ? chkp[j + 2] : -1;
    int d3 = (j + 3 < nch) ? chkp[j + 3] : -1;
    int a2, a3;
    ADDR(d2, a2);
    CONSUME(d0, P0, 0)
    P0 = (a2 >= 0) ? src4[a2] : z4;               // prefetch j+2 (overlaps j+1)
    ADDR(d3, a3);
    CONSUME(d1, P1, 64)
    P1 = (a3 >= 0) ? src4[a3] : z4;               // prefetch j+3
    d0 = d2; d1 = d3;
  }
  WSYNC();                                         // drain ds_adds

  // ---- epilogue: bias + ReLU + bf16 pack, coalesced row write ----
  const int r_ = l >> 2;
  const int orow = r0 + r_;
  if (orow < N_VOX) {
    const int flip = (r_ & 1) << 4;
    unsigned int ov[4];
#pragma unroll
    for (int w = 0; w < 4; w++) {
      int cp = ((l & 3) << 3) + (w << 1);
      float x0 = acc_s[r_ * 32 + (cp ^ flip)] + bias[cp];
      float x1 = acc_s[r_ * 32 + ((cp + 1) ^ flip)] + bias[cp + 1];
      x0 = fmaxf(x0, 0.f); x1 = fmaxf(x1, 0.f);
      ov[w] = pk_bf16(x0, x1);
    }
    uint4 o = {ov[0], ov[1], ov[2], ov[3]};
    ((uint4*)dst)[orow * 4 + (l & 3)] = o;
  }
}

// ============================ logits kernel (bf16 inputs) ===================
__global__ __launch_bounds__(256) void k_logits(
    const uint4* __restrict__ A4, const uint4* __restrict__ B4,
    const float* __restrict__ Wl, const float* __restrict__ bl,
    float* __restrict__ out) {
  __shared__ float sWl[CH * NCLS];
  __shared__ float sbl[NCLS];
  int tid = threadIdx.x;
  if (tid < CH * NCLS / 4) ((float4*)sWl)[tid] = ((const float4*)Wl)[tid];
  if (tid < NCLS) sbl[tid] = bl[tid];
  __syncthreads();
  int row = blockIdx.x * 256 + tid;
  if (row >= N_VOX) return;
  float acc[NCLS];
#pragma unroll
  for (int j = 0; j < NCLS; j++) acc[j] = sbl[j];
#pragma unroll
  for (int q = 0; q < 4; q++) {
    uint4 a = A4[row * 4 + q], b = B4[row * 4 + q];
    unsigned int au[4] = {a.x, a.y, a.z, a.w}, bu[4] = {b.x, b.y, b.z, b.w};
#pragma unroll
    for (int t = 0; t < 4; t++) {
      int c = (q << 3) + (t << 1);
      float x0 = bf_lo(au[t]) + bf_lo(bu[t]);
      float x1 = bf_hi(au[t]) + bf_hi(bu[t]);
#pragma unroll
      for (int j = 0; j < NCLS; j++) {
        acc[j] = fmaf(x0, sWl[c * NCLS + j], acc[j]);
        acc[j] = fmaf(x1, sWl[(c + 1) * NCLS + j], acc[j]);
      }
    }
  }
  float4* op = (float4*)(out + row * NCLS);
#pragma unroll
  for (int j5 = 0; j5 < NCLS / 4; j5++) {
    float4 v = {acc[j5 * 4], acc[j5 * 4 + 1], acc[j5 * 4 + 2], acc[j5 * 4 + 3]};
    op[j5] = v;
  }
}

// ============================ launch ========================================
extern "C" void kernel_launch(void* const* d_in, const int* in_sizes, int n_in,
                              void* d_out, int out_size, void* d_ws, size_t ws_size,
                              hipStream_t stream) {
  const float* in_feats = (const float*)d_in[0];
  const int*   ga       = (const int*)d_in[1];
  const int*   sa       = (const int*)d_in[2];
  const int*   gb       = (const int*)d_in[3];
  const int*   sb       = (const int*)d_in[4];
  const float* w1       = (const float*)d_in[5];
  const float* b1       = (const float*)d_in[6];
  const float* w1_2     = (const float*)d_in[7];
  const float* b1_2     = (const float*)d_in[8];
  const float* w2       = (const float*)d_in[9];
  const float* b2       = (const float*)d_in[10];
  const float* w3       = (const float*)d_in[11];
  const float* b3       = (const float*)d_in[12];
  const float* wl       = (const float*)d_in[13];
  const float* bl       = (const float*)d_in[14];
  float* out = (float*)d_out;

  // ---- workspace carve-up (u32 units, ~74 MB total) ----
  unsigned int* wsu = (unsigned int*)d_ws;
  size_t o = 0;
  unsigned int* bufA = wsu + o; o += (size_t)MPAD * 16;
  unsigned int* bufB = wsu + o; o += (size_t)MPAD * 16;
  unsigned int* bufC = wsu + o; o += (size_t)MPAD * 16;
  unsigned int* inbf = wsu + o; o += (size_t)MPAD * 16;
  unsigned int* Wg1   = wsu + o; o += WG_U32;
  unsigned int* Wg1_2 = wsu + o; o += WG_U32;
  unsigned int* Wg2   = wsu + o; o += WG_U32;
  unsigned int* Wg3   = wsu + o; o += WG_U32;
  int* off_a = (int*)(wsu + o); o += MPAD;
  int* off_b = (int*)(wsu + o); o += MPAD;
  int* cnt_a = (int*)(wsu + o); o += MPAD;
  int* cnt_b = (int*)(wsu + o); o += MPAD;
  int* tmp   = (int*)(wsu + o); o += MPAD;
  int* part  = (int*)(wsu + o); o += 1024;
  int* pl_a  = (int*)(wsu + o); o += TOT;
  int* pl_b  = (int*)(wsu + o); o += TOT;

  dim3 blk(256);
  const int g_tot  = (TOT + 255) / 256;       // 15821
  const int g_pad  = NPART;                   // 586
  const int g_conv = MPAD / 128;              // 1172 blocks x 512 thr
  const int g_wp   = (WG_U32 + 255) / 256;    // 54
  const int g_bf   = 2344;
  const int g_lg   = (N_VOX + 255) / 256;

  // ---- build inverted CSRs ----
  hipMemsetAsync(cnt_a, 0, 2 * (size_t)MPAD * sizeof(int), stream);
  k_hist<<<g_tot, blk, 0, stream>>>(sa, cnt_a);
  k_hist<<<g_tot, blk, 0, stream>>>(sb, cnt_b);
  k_scan1<<<g_pad, blk, 0, stream>>>(cnt_a, tmp, part);
  k_scan2<<<1, 1024, 0, stream>>>(part);
  k_scan3<<<g_pad, blk, 0, stream>>>(tmp, part, off_a);
  k_scan1<<<g_pad, blk, 0, stream>>>(cnt_b, tmp, part);
  k_scan2<<<1, 1024, 0, stream>>>(part);
  k_scan3<<<g_pad, blk, 0, stream>>>(tmp, part, off_b);
  hipMemsetAsync(cnt_a, 0, 2 * (size_t)MPAD * sizeof(int), stream);
  k_fill<<<g_tot, blk, 0, stream>>>(ga, sa, off_a, cnt_a, pl_a);
  k_fill<<<g_tot, blk, 0, stream>>>(gb, sb, off_b, cnt_b, pl_b);

  // ---- weight prep + activation convert ----
  k_wprep<<<g_wp, blk, 0, stream>>>(w1,   Wg1);
  k_wprep<<<g_wp, blk, 0, stream>>>(w1_2, Wg1_2);
  k_wprep<<<g_wp, blk, 0, stream>>>(w2,   Wg2);
  k_wprep<<<g_wp, blk, 0, stream>>>(w3,   Wg3);
  k_tobf<<<g_bf, blk, 0, stream>>>((const float4*)in_feats, (uint4*)inbf);

  // ---- 4 MFMA conv layers ----
  k_conv<<<g_conv, dim3(512), 0, stream>>>((const uint4*)inbf, bufA, off_a, pl_a,
                                           (const uint4*)Wg1, b1);
  k_conv<<<g_conv, dim3(512), 0, stream>>>((const uint4*)bufA, bufB, off_b, pl_b,
                                           (const uint4*)Wg1_2, b1_2);
  k_conv<<<g_conv, dim3(512), 0, stream>>>((const uint4*)inbf, bufC, off_b, pl_b,
                                           (const uint4*)Wg2, b2);
  k_conv<<<g_conv, dim3(512), 0, stream>>>((const uint4*)bufC, bufA, off_a, pl_a,
                                           (const uint4*)Wg3, b3);

  // ---- logits ----
  k_logits<<<g_lg, blk, 0, stream>>>((const uint4*)bufB, (const uint4*)bufA,
                                     wl, bl, out);
}

// Round 5
// 3875.469 us; speedup vs baseline: 1.0537x; 1.0537x over previous
//
#include <hip/hip_runtime.h>
#include <hip/hip_bf16.h>

#define N_VOX 150000
#define CH 32
#define KVOL 27
#define NCLS 20
#define TOT (KVOL * N_VOX)          // 4,050,000
#define MPAD 150016
#define NPART 586                   // MPAD / 256
#define BCAP 576                    // per-wave bucket capacity (mean 432, +6.9 sigma)
#define WG_U32 (KVOL * 512)         // 13824 u32 per prepped weight set

typedef __attribute__((ext_vector_type(4))) float f32x4;
typedef __attribute__((ext_vector_type(8))) short short8;

#define WSYNC() asm volatile("s_waitcnt lgkmcnt(0)" ::: "memory")

__device__ __forceinline__ unsigned int pk_bf16(float a, float b) {
  unsigned int ua = __float_as_uint(a), ub = __float_as_uint(b);
  ua = ua + 0x7FFFu + ((ua >> 16) & 1u);     // RNE
  ub = ub + 0x7FFFu + ((ub >> 16) & 1u);
  return (ub & 0xFFFF0000u) | (ua >> 16);
}
__device__ __forceinline__ float bf_lo(unsigned int u) { return __uint_as_float(u << 16); }
__device__ __forceinline__ float bf_hi(unsigned int u) { return __uint_as_float(u & 0xFFFF0000u); }

// ============================ rulebook inversion ============================

__global__ __launch_bounds__(256) void k_hist(const int* __restrict__ sidx,
                                              int* __restrict__ cnt) {
  int e = blockIdx.x * 256 + threadIdx.x;
  if (e < TOT) atomicAdd(&cnt[sidx[e]], 1);
}

__global__ __launch_bounds__(256) void k_scan1(const int* __restrict__ cnt,
                                               int* __restrict__ tmp,
                                               int* __restrict__ part) {
  __shared__ int sb[256];
  int t = threadIdx.x;
  int gt = blockIdx.x * 256 + t;
  int v = cnt[gt];
  sb[t] = v;
  __syncthreads();
  for (int s = 1; s < 256; s <<= 1) {
    int a = (t >= s) ? sb[t - s] : 0;
    __syncthreads();
    sb[t] += a;
    __syncthreads();
  }
  tmp[gt] = sb[t] - v;
  if (t == 255) part[blockIdx.x] = sb[t];
}

__global__ __launch_bounds__(1024) void k_scan2(int* __restrict__ part) {
  __shared__ int sb[1024];
  int t = threadIdx.x;
  int v = (t < NPART) ? part[t] : 0;
  sb[t] = v;
  __syncthreads();
  for (int s = 1; s < 1024; s <<= 1) {
    int a = (t >= s) ? sb[t - s] : 0;
    __syncthreads();
    sb[t] += a;
    __syncthreads();
  }
  if (t < NPART) part[t] = sb[t] - v;
}

__global__ __launch_bounds__(256) void k_scan3(const int* __restrict__ tmp,
                                               const int* __restrict__ part,
                                               int* __restrict__ off) {
  int gt = blockIdx.x * 256 + threadIdx.x;
  off[gt] = tmp[gt] + part[blockIdx.x];
}

__global__ __launch_bounds__(256) void k_fill(const int* __restrict__ gidx,
                                              const int* __restrict__ sidx,
                                              const int* __restrict__ off,
                                              int* __restrict__ cur,
                                              int* __restrict__ pl) {
  int e = blockIdx.x * 256 + threadIdx.x;
  if (e >= TOT) return;
  int k = e / N_VOX;
  int s = sidx[e];
  int pos = atomicAdd(&cur[s], 1);
  pl[off[s] + pos] = (gidx[e] << 5) | k;
}

// ============================ weight prep (f32 -> B-frag bf16) ==============
__global__ __launch_bounds__(256) void k_wprep(const float* __restrict__ W,
                                               unsigned int* __restrict__ out) {
  int i = blockIdx.x * 256 + threadIdx.x;
  if (i >= WG_U32) return;
  int k = i >> 9, r = i & 511;
  int h = r >> 8, l = (r >> 2) & 63, w = r & 3;
  int ci0 = ((l >> 4) << 3) + (w << 1);
  int co = (l & 15) + (h << 4);
  const float* wk = W + k * 1024;
  out[i] = pk_bf16(wk[ci0 * 32 + co], wk[(ci0 + 1) * 32 + co]);
}

// ============================ f32 -> bf16 activation convert ================
__global__ __launch_bounds__(256) void k_tobf(const float4* __restrict__ in4,
                                              uint4* __restrict__ out4) {
  int i = blockIdx.x * 256 + threadIdx.x;
  if (i >= (N_VOX * CH) / 8) return;   // 600000
  float4 f0 = in4[i * 2], f1 = in4[i * 2 + 1];
  uint4 o;
  o.x = pk_bf16(f0.x, f0.y); o.y = pk_bf16(f0.z, f0.w);
  o.z = pk_bf16(f1.x, f1.y); o.w = pk_bf16(f1.z, f1.w);
  out4[i] = o;
}

// ============================ MFMA conv kernel ==============================
// Block = 256 thr = 4 waves, ~19.5 KB LDS -> high occupancy, NO __syncthreads.
// Each wave owns 16 output rows: bucket CSR entries by k, then per 16-entry
// chunk gather rows from global DIRECTLY into the MFMA A-fragment (lane l
// holds 16B of row (l&15) at offset (l>>4)*16 -- one dwordx4, no LDS stage),
// B-frags from global (L1/L2-hot), 2x mfma_16x16x32_bf16, swizzled LDS
// ds_add scatter into per-wave f32 accumulator. 2-deep register pipeline.

__device__ __forceinline__ void pre_chunk(
    int j, int nch, const int* chkp, const int* kep,
    const unsigned int* bkt, const uint4* __restrict__ src4,
    const uint4* __restrict__ Wg4,
    int am, int ah, int l,
    int& cb, int& ke, uint4& av, uint4& bv0, uint4& bv1) {
  if (j < nch) {
    int d = chkp[j];
    int k = d >> 10;
    cb = d & 1023;
    int e = kep[k];
    if (e > BCAP) e = BCAP;
    ke = e;
    int sc = cb + am;
    if (sc > e - 1) sc = e - 1;            // clamp: duplicate last valid entry
    int gi = (int)(bkt[sc] >> 4);
    av = src4[gi * 4 + ah];                // A-frag piece = 16B of the row
    bv0 = Wg4[k * 128 + l];
    bv1 = Wg4[k * 128 + 64 + l];
  } else {
    cb = 0; ke = 0;
  }
}

__device__ __forceinline__ void consume_chunk(
    int cb, int ke, uint4 av, uint4 bv0, uint4 bv1,
    const unsigned int* bkt, float* acc_s, int e0, int co) {
  const f32x4 cz = {0.f, 0.f, 0.f, 0.f};
  union { uint4 u; short8 s; } ua, ub0, ub1;
  ua.u = av; ub0.u = bv0; ub1.u = bv1;
  f32x4 c0 = __builtin_amdgcn_mfma_f32_16x16x32_bf16(ua.s, ub0.s, cz, 0, 0, 0);
  f32x4 c1 = __builtin_amdgcn_mfma_f32_16x16x32_bf16(ua.s, ub1.s, cz, 0, 0, 0);
#pragma unroll
  for (int r = 0; r < 4; r++) {
    int s2 = cb + e0 + r;
    if (s2 < ke) {
      int lr = (int)(bkt[s2] & 15u);
      int sw = co ^ ((lr & 1) << 4);
      atomicAdd(&acc_s[lr * 32 + sw], c0[r]);
      atomicAdd(&acc_s[lr * 32 + (sw ^ 16)], c1[r]);
    }
  }
}

__global__ __launch_bounds__(256, 4) void k_conv(
    const uint4* __restrict__ src4, unsigned int* __restrict__ dst,
    const int* __restrict__ off, const int* __restrict__ pl,
    const uint4* __restrict__ Wg4, const float* __restrict__ bias) {
  __shared__ float sAcc[4][512];                 // 16 x 32 f32/wave, XOR-swizzled
  __shared__ unsigned int sBkt[4][BCAP];         // (gi<<4)|lrow
  __shared__ int sKb[4][32], sKe[4][32];
  __shared__ int sChk[4][64];                    // counts, then chunk descs
  __shared__ int sNch[4];

  const int tid = threadIdx.x;
  const int wv = tid >> 6, l = tid & 63;
  const int r0 = (blockIdx.x * 4 + wv) * 16;

  float* acc_s = sAcc[wv];
  unsigned int* bkt = sBkt[wv];
  int* kb = sKb[wv];
  int* kep = sKe[wv];
  int* chkp = sChk[wv];

  for (int i = l; i < 512; i += 64) acc_s[i] = 0.f;
  if (l < 32) chkp[l] = 0;                       // counts
  WSYNC();

  // ---- bucket by k (4 lanes per row) ----
  const int rr_ = l >> 2, jj = l & 3;
  const int row_g = r0 + rr_;
  int eb = 0, ee = 0;
  if (row_g < N_VOX) { eb = off[row_g]; ee = off[row_g + 1]; }

  for (int i = eb + jj; i < ee; i += 4) atomicAdd(&chkp[pl[i] & 31], 1);
  WSYNC();
  if (l == 0) {
    int s = 0;
    for (int k = 0; k < KVOL; k++) { kb[k] = s; kep[k] = s; s += chkp[k]; }
  }
  WSYNC();
  for (int i = eb + jj; i < ee; i += 4) {
    int p = pl[i];
    int pos = atomicAdd(&kep[p & 31], 1);        // kep becomes per-k end
    if (pos < BCAP) bkt[pos] = (unsigned int)((((unsigned int)p >> 5) << 4) | (unsigned int)rr_);
  }
  WSYNC();

  // ---- flatten chunk descriptor list ----
  if (l == 0) {
    int n = 0;
    for (int k = 0; k < KVOL; k++) {
      int b = kb[k], e = kep[k];
      if (e > BCAP) e = BCAP;
      for (int cb = b; cb < e; cb += 16) chkp[n++] = (k << 10) | cb;
    }
    sNch[wv] = n;
  }
  WSYNC();
  const int nch = sNch[wv];

  // ---- pipelined main loop (2-deep, direct-to-A-frag gather) ----
  const int am = l & 15, ah = l >> 4;            // A-frag: entry am, 16B piece ah
  const int e0 = ah << 2, co = l & 15;           // C scatter

  int cb0 = 0, ke0 = 0, cb1 = 0, ke1 = 0, cbt = 0, ket = 0;
  uint4 A0 = {}, B00 = {}, B01 = {}, A1 = {}, B10 = {}, B11 = {};
  uint4 At = {}, Bt0 = {}, Bt1 = {};
  pre_chunk(0, nch, chkp, kep, bkt, src4, Wg4, am, ah, l, cb0, ke0, A0, B00, B01);
  pre_chunk(1, nch, chkp, kep, bkt, src4, Wg4, am, ah, l, cb1, ke1, A1, B10, B11);

  for (int j = 0; j < nch; j += 2) {
    pre_chunk(j + 2, nch, chkp, kep, bkt, src4, Wg4, am, ah, l, cbt, ket, At, Bt0, Bt1);
    consume_chunk(cb0, ke0, A0, B00, B01, bkt, acc_s, e0, co);
    cb0 = cbt; ke0 = ket; A0 = At; B00 = Bt0; B01 = Bt1;
    pre_chunk(j + 3, nch, chkp, kep, bkt, src4, Wg4, am, ah, l, cbt, ket, At, Bt0, Bt1);
    if (j + 1 < nch)
      consume_chunk(cb1, ke1, A1, B10, B11, bkt, acc_s, e0, co);
    cb1 = cbt; ke1 = ket; A1 = At; B10 = Bt0; B11 = Bt1;
  }
  WSYNC();                                       // drain ds_adds

  // ---- epilogue: bias + ReLU + bf16 pack, coalesced row write ----
  const int r_ = l >> 2;
  const int orow = r0 + r_;
  if (orow < N_VOX) {
    const int flip = (r_ & 1) << 4;
    unsigned int ov[4];
#pragma unroll
    for (int w = 0; w < 4; w++) {
      int cp = ((l & 3) << 3) + (w << 1);
      float x0 = acc_s[r_ * 32 + (cp ^ flip)] + bias[cp];
      float x1 = acc_s[r_ * 32 + ((cp + 1) ^ flip)] + bias[cp + 1];
      x0 = fmaxf(x0, 0.f); x1 = fmaxf(x1, 0.f);
      ov[w] = pk_bf16(x0, x1);
    }
    uint4 o = {ov[0], ov[1], ov[2], ov[3]};
    ((uint4*)dst)[orow * 4 + (l & 3)] = o;
  }
}

// ============================ logits kernel (bf16 inputs) ===================
__global__ __launch_bounds__(256) void k_logits(
    const uint4* __restrict__ A4, const uint4* __restrict__ B4,
    const float* __restrict__ Wl, const float* __restrict__ bl,
    float* __restrict__ out) {
  __shared__ float sWl[CH * NCLS];
  __shared__ float sbl[NCLS];
  int tid = threadIdx.x;
  if (tid < CH * NCLS / 4) ((float4*)sWl)[tid] = ((const float4*)Wl)[tid];
  if (tid < NCLS) sbl[tid] = bl[tid];
  __syncthreads();
  int row = blockIdx.x * 256 + tid;
  if (row >= N_VOX) return;
  float acc[NCLS];
#pragma unroll
  for (int j = 0; j < NCLS; j++) acc[j] = sbl[j];
#pragma unroll
  for (int q = 0; q < 4; q++) {
    uint4 a = A4[row * 4 + q], b = B4[row * 4 + q];
    unsigned int au[4] = {a.x, a.y, a.z, a.w}, bu[4] = {b.x, b.y, b.z, b.w};
#pragma unroll
    for (int t = 0; t < 4; t++) {
      int c = (q << 3) + (t << 1);
      float x0 = bf_lo(au[t]) + bf_lo(bu[t]);
      float x1 = bf_hi(au[t]) + bf_hi(bu[t]);
#pragma unroll
      for (int j = 0; j < NCLS; j++) {
        acc[j] = fmaf(x0, sWl[c * NCLS + j], acc[j]);
        acc[j] = fmaf(x1, sWl[(c + 1) * NCLS + j], acc[j]);
      }
    }
  }
  float4* op = (float4*)(out + row * NCLS);
#pragma unroll
  for (int j5 = 0; j5 < NCLS / 4; j5++) {
    float4 v = {acc[j5 * 4], acc[j5 * 4 + 1], acc[j5 * 4 + 2], acc[j5 * 4 + 3]};
    op[j5] = v;
  }
}

// ============================ launch ========================================
extern "C" void kernel_launch(void* const* d_in, const int* in_sizes, int n_in,
                              void* d_out, int out_size, void* d_ws, size_t ws_size,
                              hipStream_t stream) {
  const float* in_feats = (const float*)d_in[0];
  const int*   ga       = (const int*)d_in[1];
  const int*   sa       = (const int*)d_in[2];
  const int*   gb       = (const int*)d_in[3];
  const int*   sb       = (const int*)d_in[4];
  const float* w1       = (const float*)d_in[5];
  const float* b1       = (const float*)d_in[6];
  const float* w1_2     = (const float*)d_in[7];
  const float* b1_2     = (const float*)d_in[8];
  const float* w2       = (const float*)d_in[9];
  const float* b2       = (const float*)d_in[10];
  const float* w3       = (const float*)d_in[11];
  const float* b3       = (const float*)d_in[12];
  const float* wl       = (const float*)d_in[13];
  const float* bl       = (const float*)d_in[14];
  float* out = (float*)d_out;

  // ---- workspace carve-up (u32 units, ~74 MB total) ----
  unsigned int* wsu = (unsigned int*)d_ws;
  size_t o = 0;
  unsigned int* bufA = wsu + o; o += (size_t)MPAD * 16;
  unsigned int* bufB = wsu + o; o += (size_t)MPAD * 16;
  unsigned int* bufC = wsu + o; o += (size_t)MPAD * 16;
  unsigned int* inbf = wsu + o; o += (size_t)MPAD * 16;
  unsigned int* Wg1   = wsu + o; o += WG_U32;
  unsigned int* Wg1_2 = wsu + o; o += WG_U32;
  unsigned int* Wg2   = wsu + o; o += WG_U32;
  unsigned int* Wg3   = wsu + o; o += WG_U32;
  int* off_a = (int*)(wsu + o); o += MPAD;
  int* off_b = (int*)(wsu + o); o += MPAD;
  int* cnt_a = (int*)(wsu + o); o += MPAD;
  int* cnt_b = (int*)(wsu + o); o += MPAD;
  int* tmp   = (int*)(wsu + o); o += MPAD;
  int* part  = (int*)(wsu + o); o += 1024;
  int* pl_a  = (int*)(wsu + o); o += TOT;
  int* pl_b  = (int*)(wsu + o); o += TOT;

  dim3 blk(256);
  const int g_tot  = (TOT + 255) / 256;       // 15821
  const int g_pad  = NPART;                   // 586
  const int g_conv = MPAD / 64;               // 2344 blocks x 256 thr (4 waves)
  const int g_wp   = (WG_U32 + 255) / 256;    // 54
  const int g_bf   = 2344;
  const int g_lg   = (N_VOX + 255) / 256;

  // ---- build inverted CSRs ----
  hipMemsetAsync(cnt_a, 0, 2 * (size_t)MPAD * sizeof(int), stream);
  k_hist<<<g_tot, blk, 0, stream>>>(sa, cnt_a);
  k_hist<<<g_tot, blk, 0, stream>>>(sb, cnt_b);
  k_scan1<<<g_pad, blk, 0, stream>>>(cnt_a, tmp, part);
  k_scan2<<<1, 1024, 0, stream>>>(part);
  k_scan3<<<g_pad, blk, 0, stream>>>(tmp, part, off_a);
  k_scan1<<<g_pad, blk, 0, stream>>>(cnt_b, tmp, part);
  k_scan2<<<1, 1024, 0, stream>>>(part);
  k_scan3<<<g_pad, blk, 0, stream>>>(tmp, part, off_b);
  hipMemsetAsync(cnt_a, 0, 2 * (size_t)MPAD * sizeof(int), stream);
  k_fill<<<g_tot, blk, 0, stream>>>(ga, sa, off_a, cnt_a, pl_a);
  k_fill<<<g_tot, blk, 0, stream>>>(gb, sb, off_b, cnt_b, pl_b);

  // ---- weight prep + activation convert ----
  k_wprep<<<g_wp, blk, 0, stream>>>(w1,   Wg1);
  k_wprep<<<g_wp, blk, 0, stream>>>(w1_2, Wg1_2);
  k_wprep<<<g_wp, blk, 0, stream>>>(w2,   Wg2);
  k_wprep<<<g_wp, blk, 0, stream>>>(w3,   Wg3);
  k_tobf<<<g_bf, blk, 0, stream>>>((const float4*)in_feats, (uint4*)inbf);

  // ---- 4 MFMA conv layers ----
  k_conv<<<g_conv, blk, 0, stream>>>((const uint4*)inbf, bufA, off_a, pl_a,
                                     (const uint4*)Wg1, b1);
  k_conv<<<g_conv, blk, 0, stream>>>((const uint4*)bufA, bufB, off_b, pl_b,
                                     (const uint4*)Wg1_2, b1_2);
  k_conv<<<g_conv, blk, 0, stream>>>((const uint4*)inbf, bufC, off_b, pl_b,
                                     (const uint4*)Wg2, b2);
  k_conv<<<g_conv, blk, 0, stream>>>((const uint4*)bufC, bufA, off_a, pl_a,
                                     (const uint4*)Wg3, b3);

  // ---- logits ----
  k_logits<<<g_lg, blk, 0, stream>>>((const uint4*)bufB, (const uint4*)bufA,
                                     wl, bl, out);
}

// Round 6
// 3616.913 us; speedup vs baseline: 1.1290x; 1.0715x over previous
//
#include <hip/hip_runtime.h>
#include <hip/hip_bf16.h>

#define N_VOX 150000
#define CH 32
#define KVOL 27
#define NCLS 20
#define TOT (KVOL * N_VOX)          // 4,050,000
#define MPAD 150016
#define NW 4688                     // 32-row groups (MPAD/32)
#define NBINS (KVOL * NW)           // 126576
#define NBPAD 126720                // 495 * 256
#define NB1 495
#define MAXCH 144
#define WG_U32 (KVOL * 512)         // 13824 u32 per prepped weight set

typedef __attribute__((ext_vector_type(4))) float f32x4;
typedef __attribute__((ext_vector_type(8))) short short8;

#define WSYNC() asm volatile("s_waitcnt lgkmcnt(0)" ::: "memory")

__device__ __forceinline__ unsigned int pk_bf16(float a, float b) {
  unsigned int ua = __float_as_uint(a), ub = __float_as_uint(b);
  ua = ua + 0x7FFFu + ((ua >> 16) & 1u);     // RNE
  ub = ub + 0x7FFFu + ((ub >> 16) & 1u);
  return (ub & 0xFFFF0000u) | (ua >> 16);
}
__device__ __forceinline__ float bf_lo(unsigned int u) { return __uint_as_float(u << 16); }
__device__ __forceinline__ float bf_hi(unsigned int u) { return __uint_as_float(u & 0xFFFF0000u); }

// ==================== build: (k, row-group) keyed CSR =======================

__global__ __launch_bounds__(256) void k_hist2(
    const int* __restrict__ sa, const int* __restrict__ sb,
    int* __restrict__ cnt2) {
  int i = blockIdx.x * 256 + threadIdx.x;
  if (i >= N_VOX) return;
  int k = blockIdx.y;
  const int* s_ = blockIdx.z ? sb : sa;
  int sv = s_[k * N_VOX + i];
  atomicAdd(&cnt2[blockIdx.z * NBPAD + k * NW + (sv >> 5)], 1);
}

__global__ __launch_bounds__(256) void k_scan1(const int* __restrict__ cnt2,
                                               int* __restrict__ off2,
                                               int* __restrict__ part) {
  __shared__ int sb_[256];
  int t = threadIdx.x;
  int gt = blockIdx.y * NBPAD + blockIdx.x * 256 + t;
  int v = cnt2[gt];
  sb_[t] = v;
  __syncthreads();
  for (int s = 1; s < 256; s <<= 1) {
    int a = (t >= s) ? sb_[t - s] : 0;
    __syncthreads();
    sb_[t] += a;
    __syncthreads();
  }
  off2[gt] = sb_[t] - v;
  if (t == 255) part[blockIdx.y * 512 + blockIdx.x] = sb_[t];
}

__global__ __launch_bounds__(512) void k_scan2(int* __restrict__ part) {
  __shared__ int sb_[512];
  int t = threadIdx.x;
  int v = (t < NB1) ? part[blockIdx.x * 512 + t] : 0;
  sb_[t] = v;
  __syncthreads();
  for (int s = 1; s < 512; s <<= 1) {
    int a = (t >= s) ? sb_[t - s] : 0;
    __syncthreads();
    sb_[t] += a;
    __syncthreads();
  }
  if (t < NB1) part[blockIdx.x * 512 + t] = sb_[t] - v;
}

__global__ __launch_bounds__(256) void k_scan3(int* __restrict__ off2,
                                               const int* __restrict__ part) {
  int gt = blockIdx.y * NBPAD + blockIdx.x * 256 + threadIdx.x;
  off2[gt] += part[blockIdx.y * 512 + blockIdx.x];
}

__global__ __launch_bounds__(256) void k_fill2(
    const int* __restrict__ ga, const int* __restrict__ sa,
    const int* __restrict__ gb, const int* __restrict__ sb,
    const int* __restrict__ off2, int* __restrict__ cur2,
    unsigned int* __restrict__ plA, unsigned int* __restrict__ plB) {
  int i = blockIdx.x * 256 + threadIdx.x;
  if (i >= N_VOX) return;
  int k = blockIdx.y;
  const int* s_ = blockIdx.z ? sb : sa;
  const int* g_ = blockIdx.z ? gb : ga;
  unsigned int* pl = blockIdx.z ? plB : plA;
  int e = k * N_VOX + i;
  int sv = s_[e];
  int q = blockIdx.z * NBPAD + k * NW + (sv >> 5);
  int pos = atomicAdd(&cur2[q], 1);
  pl[off2[q] + pos] = ((unsigned int)g_[e] << 5) | (unsigned int)(sv & 31);
}

// ==================== weight prep (f32 -> B-frag bf16) ======================
__global__ __launch_bounds__(256) void k_wprep(const float* __restrict__ W,
                                               unsigned int* __restrict__ out) {
  int i = blockIdx.x * 256 + threadIdx.x;
  if (i >= WG_U32) return;
  int k = i >> 9, r = i & 511;
  int h = r >> 8, l = (r >> 2) & 63, w = r & 3;
  int ci0 = ((l >> 4) << 3) + (w << 1);
  int co = (l & 15) + (h << 4);
  const float* wk = W + k * 1024;
  out[i] = pk_bf16(wk[ci0 * 32 + co], wk[(ci0 + 1) * 32 + co]);
}

// ==================== f32 -> bf16 activation convert ========================
__global__ __launch_bounds__(256) void k_tobf(const float4* __restrict__ in4,
                                              uint4* __restrict__ out4) {
  int i = blockIdx.x * 256 + threadIdx.x;
  if (i >= (N_VOX * CH) / 8) return;
  float4 f0 = in4[i * 2], f1 = in4[i * 2 + 1];
  uint4 o;
  o.x = pk_bf16(f0.x, f0.y); o.y = pk_bf16(f0.z, f0.w);
  o.z = pk_bf16(f1.x, f1.y); o.w = pk_bf16(f1.z, f1.w);
  out4[i] = o;
}

// ==================== MFMA conv kernel ======================================
// Block = 256 thr = 4 waves. Each wave owns 32 output rows (one NW group).
// Pre-bucketed CSR: for each k, the wave's entries are CONTIGUOUS in pl2
// (payload = (gi<<5)|(row&31)). Per 16-entry chunk: payload load (dist 8),
// gather rows direct into MFMA A-frag + B from global (dist 4), 2x
// mfma_16x16x32_bf16, swizzled LDS atomic scatter. Fully static rings.

#define PVLOAD(PS, J) { \
  int s_ = chS[(J)]; int c_ = (chM[(J)] & 255) - 1; \
  int o_ = l & 15; if (o_ > c_) o_ = (c_ < 0) ? 0 : c_; \
  PV##PS = pl2[s_ + o_]; }

#define ALOAD(AS, PS, J) { \
  unsigned int gi_ = PV##PS >> 5; \
  A##AS = src4[gi_ * 4 + ah]; \
  int k_ = chM[(J)] >> 8; \
  B##AS##0 = Wg4[k_ * 128 + l]; \
  B##AS##1 = Wg4[k_ * 128 + 64 + l]; }

#define CONSUME(AS, PS, J) { \
  int c_ = chM[(J)] & 255; \
  union { uint4 u; short8 s; } ua_, ub0_, ub1_; \
  ua_.u = A##AS; ub0_.u = B##AS##0; ub1_.u = B##AS##1; \
  f32x4 c0_ = __builtin_amdgcn_mfma_f32_16x16x32_bf16(ua_.s, ub0_.s, cz, 0, 0, 0); \
  f32x4 c1_ = __builtin_amdgcn_mfma_f32_16x16x32_bf16(ua_.s, ub1_.s, cz, 0, 0, 0); \
  _Pragma("unroll") for (int r_ = 0; r_ < 4; r_++) { \
    int s2_ = e0 + r_; \
    int pvr_ = __shfl((int)PV##PS, s2_); \
    if (s2_ < c_) { \
      int lr_ = pvr_ & 31; \
      int sw_ = co ^ ((lr_ & 1) << 4); \
      atomicAdd(&acc_s[lr_ * 32 + sw_], c0_[r_]); \
      atomicAdd(&acc_s[lr_ * 32 + (sw_ ^ 16)], c1_[r_]); \
    } } }

__global__ __launch_bounds__(256, 4) void k_conv(
    const uint4* __restrict__ src4, unsigned int* __restrict__ dst,
    const int* __restrict__ offW, const unsigned int* __restrict__ pl2,
    const uint4* __restrict__ Wg4, const float* __restrict__ bias) {
  __shared__ float sAcc[4][1024];       // 32 rows x 32 cols f32, XOR-swizzled
  __shared__ int sChS[4][MAXCH];        // chunk start (global entry idx)
  __shared__ int sChM[4][MAXCH];        // (k<<8)|cnt

  const int tid = threadIdx.x;
  const int wv = tid >> 6, l = tid & 63;
  const int w = blockIdx.x * 4 + wv;    // group id < NW

  float* acc_s = sAcc[wv];
  int* chS = sChS[wv];
  int* chM = sChM[wv];

  for (int i = l; i < 1024; i += 64) acc_s[i] = 0.f;

  // ---- preamble: 27 contiguous ranges -> flattened chunk descriptors ----
  int st = 0, len = 0;
  if (l < KVOL) {
    st = offW[l * NW + w];
    len = offW[l * NW + w + 1] - st;
  }
  int nck = (len + 15) >> 4;
  if (nck > 5) nck = 5;
  int pfx = nck;
#pragma unroll
  for (int s = 1; s < 32; s <<= 1) {
    int t2 = __shfl_up(pfx, s);
    if (l >= s) pfx += t2;
  }
  const int total = __shfl(pfx, 26);
  int base = pfx - nck;
  if (l < KVOL) {
    for (int c = 0; c < nck; c++) {
      int cnt = len - (c << 4);
      if (cnt > 16) cnt = 16;
      chS[base + c] = st + (c << 4);
      chM[base + c] = (l << 8) | cnt;
    }
  }
  for (int j2 = total + l; j2 < MAXCH; j2 += 64) { chS[j2] = 0; chM[j2] = 0; }
  WSYNC();

  const int nch8 = (total + 7) & ~7;
  const f32x4 cz = {0.f, 0.f, 0.f, 0.f};
  const int ah = l >> 4;                // A-frag 16B piece
  const int e0 = (l >> 4) << 2;         // C scatter entry base
  const int co = l & 15;                // C scatter col

  unsigned int PV0, PV1, PV2, PV3, PV4, PV5, PV6, PV7;
  uint4 A0, A1, A2, A3;
  uint4 B00, B01, B10, B11, B20, B21, B30, B31;

  // prologue: payloads for chunks 0..7, A/B for chunks 0..3
  PVLOAD(0, 0) PVLOAD(1, 1) PVLOAD(2, 2) PVLOAD(3, 3)
  PVLOAD(4, 4) PVLOAD(5, 5) PVLOAD(6, 6) PVLOAD(7, 7)
  ALOAD(0, 0, 0) ALOAD(1, 1, 1) ALOAD(2, 2, 2) ALOAD(3, 3, 3)

  for (int p = 0; p < nch8; p += 8) {
    CONSUME(0, 0, p + 0)  ALOAD(0, 4, p + 4)  PVLOAD(0, p + 8)
    CONSUME(1, 1, p + 1)  ALOAD(1, 5, p + 5)  PVLOAD(1, p + 9)
    CONSUME(2, 2, p + 2)  ALOAD(2, 6, p + 6)  PVLOAD(2, p + 10)
    CONSUME(3, 3, p + 3)  ALOAD(3, 7, p + 7)  PVLOAD(3, p + 11)
    CONSUME(0, 4, p + 4)  ALOAD(0, 0, p + 8)  PVLOAD(4, p + 12)
    CONSUME(1, 5, p + 5)  ALOAD(1, 1, p + 9)  PVLOAD(5, p + 13)
    CONSUME(2, 6, p + 6)  ALOAD(2, 2, p + 10) PVLOAD(6, p + 14)
    CONSUME(3, 7, p + 7)  ALOAD(3, 3, p + 11) PVLOAD(7, p + 15)
  }
  WSYNC();                               // drain LDS atomics

  // ---- epilogue: bias + ReLU + bf16 pack, coalesced row writes ----
#pragma unroll
  for (int half = 0; half < 2; half++) {
    int r_ = half * 16 + (l >> 2);
    int orow = w * 32 + r_;
    if (orow < N_VOX) {
      int flip = (r_ & 1) << 4;
      unsigned int ov[4];
#pragma unroll
      for (int t = 0; t < 4; t++) {
        int cp = ((l & 3) << 3) + (t << 1);
        float x0 = acc_s[r_ * 32 + (cp ^ flip)] + bias[cp];
        float x1 = acc_s[r_ * 32 + ((cp + 1) ^ flip)] + bias[cp + 1];
        ov[t] = pk_bf16(fmaxf(x0, 0.f), fmaxf(x1, 0.f));
      }
      uint4 o = {ov[0], ov[1], ov[2], ov[3]};
      ((uint4*)dst)[orow * 4 + (l & 3)] = o;
    }
  }
}

// ==================== logits kernel (bf16 inputs) ===========================
__global__ __launch_bounds__(256) void k_logits(
    const uint4* __restrict__ A4, const uint4* __restrict__ B4,
    const float* __restrict__ Wl, const float* __restrict__ bl,
    float* __restrict__ out) {
  __shared__ float sWl[CH * NCLS];
  __shared__ float sbl[NCLS];
  int tid = threadIdx.x;
  if (tid < CH * NCLS / 4) ((float4*)sWl)[tid] = ((const float4*)Wl)[tid];
  if (tid < NCLS) sbl[tid] = bl[tid];
  __syncthreads();
  int row = blockIdx.x * 256 + tid;
  if (row >= N_VOX) return;
  float acc[NCLS];
#pragma unroll
  for (int j = 0; j < NCLS; j++) acc[j] = sbl[j];
#pragma unroll
  for (int q = 0; q < 4; q++) {
    uint4 a = A4[row * 4 + q], b = B4[row * 4 + q];
    unsigned int au[4] = {a.x, a.y, a.z, a.w}, bu[4] = {b.x, b.y, b.z, b.w};
#pragma unroll
    for (int t = 0; t < 4; t++) {
      int c = (q << 3) + (t << 1);
      float x0 = bf_lo(au[t]) + bf_lo(bu[t]);
      float x1 = bf_hi(au[t]) + bf_hi(bu[t]);
#pragma unroll
      for (int j = 0; j < NCLS; j++) {
        acc[j] = fmaf(x0, sWl[c * NCLS + j], acc[j]);
        acc[j] = fmaf(x1, sWl[(c + 1) * NCLS + j], acc[j]);
      }
    }
  }
  float4* op = (float4*)(out + row * NCLS);
#pragma unroll
  for (int j5 = 0; j5 < NCLS / 4; j5++) {
    float4 v = {acc[j5 * 4], acc[j5 * 4 + 1], acc[j5 * 4 + 2], acc[j5 * 4 + 3]};
    op[j5] = v;
  }
}

// ==================== launch ================================================
extern "C" void kernel_launch(void* const* d_in, const int* in_sizes, int n_in,
                              void* d_out, int out_size, void* d_ws, size_t ws_size,
                              hipStream_t stream) {
  const float* in_feats = (const float*)d_in[0];
  const int*   ga       = (const int*)d_in[1];
  const int*   sa       = (const int*)d_in[2];
  const int*   gb       = (const int*)d_in[3];
  const int*   sb       = (const int*)d_in[4];
  const float* w1       = (const float*)d_in[5];
  const float* b1       = (const float*)d_in[6];
  const float* w1_2     = (const float*)d_in[7];
  const float* b1_2     = (const float*)d_in[8];
  const float* w2       = (const float*)d_in[9];
  const float* b2       = (const float*)d_in[10];
  const float* w3       = (const float*)d_in[11];
  const float* b3       = (const float*)d_in[12];
  const float* wl       = (const float*)d_in[13];
  const float* bl       = (const float*)d_in[14];
  float* out = (float*)d_out;

  // ---- workspace carve-up (u32 units, ~74.1 MB) ----
  unsigned int* wsu = (unsigned int*)d_ws;
  size_t o = 0;
  unsigned int* bufA = wsu + o; o += (size_t)MPAD * 16;
  unsigned int* bufB = wsu + o; o += (size_t)MPAD * 16;
  unsigned int* bufC = wsu + o; o += (size_t)MPAD * 16;
  unsigned int* inbf = wsu + o; o += (size_t)MPAD * 16;
  unsigned int* Wg1   = wsu + o; o += WG_U32;
  unsigned int* Wg1_2 = wsu + o; o += WG_U32;
  unsigned int* Wg2   = wsu + o; o += WG_U32;
  unsigned int* Wg3   = wsu + o; o += WG_U32;
  int* off2 = (int*)(wsu + o); o += 2 * NBPAD;
  int* cnt2 = (int*)(wsu + o); o += 2 * NBPAD;    // cnt2 then cur2: one memset
  int* cur2 = (int*)(wsu + o); o += 2 * NBPAD;
  int* part = (int*)(wsu + o); o += 1024;
  unsigned int* plA = wsu + o; o += TOT;
  unsigned int* plB = wsu + o; o += TOT;

  dim3 blk(256);
  dim3 gNK2(586, KVOL, 2);
  dim3 gScan(NB1, 2);
  const int g_conv = NW / 4;                 // 1172
  const int g_wp   = (WG_U32 + 255) / 256;   // 54
  const int g_bf   = 2344;
  const int g_lg   = (N_VOX + 255) / 256;

  // ---- build (k, row-group) CSRs ----
  hipMemsetAsync(cnt2, 0, 4 * (size_t)NBPAD * sizeof(int), stream);  // cnt2+cur2
  k_hist2<<<gNK2, blk, 0, stream>>>(sa, sb, cnt2);
  k_scan1<<<gScan, blk, 0, stream>>>(cnt2, off2, part);
  k_scan2<<<dim3(2), dim3(512), 0, stream>>>(part);
  k_scan3<<<gScan, blk, 0, stream>>>(off2, part);
  k_fill2<<<gNK2, blk, 0, stream>>>(ga, sa, gb, sb, off2, cur2, plA, plB);

  // ---- weight prep + activation convert ----
  k_wprep<<<g_wp, blk, 0, stream>>>(w1,   Wg1);
  k_wprep<<<g_wp, blk, 0, stream>>>(w1_2, Wg1_2);
  k_wprep<<<g_wp, blk, 0, stream>>>(w2,   Wg2);
  k_wprep<<<g_wp, blk, 0, stream>>>(w3,   Wg3);
  k_tobf<<<g_bf, blk, 0, stream>>>((const float4*)in_feats, (uint4*)inbf);

  // ---- 4 MFMA conv layers ----
  const int* offA = off2;
  const int* offB = off2 + NBPAD;
  k_conv<<<g_conv, blk, 0, stream>>>((const uint4*)inbf, bufA, offA, plA,
                                     (const uint4*)Wg1, b1);
  k_conv<<<g_conv, blk, 0, stream>>>((const uint4*)bufA, bufB, offB, plB,
                                     (const uint4*)Wg1_2, b1_2);
  k_conv<<<g_conv, blk, 0, stream>>>((const uint4*)inbf, bufC, offB, plB,
                                     (const uint4*)Wg2, b2);
  k_conv<<<g_conv, blk, 0, stream>>>((const uint4*)bufC, bufA, offA, plA,
                                     (const uint4*)Wg3, b3);

  // ---- logits ----
  k_logits<<<g_lg, blk, 0, stream>>>((const uint4*)bufB, (const uint4*)bufA,
                                     wl, bl, out);
}

// Round 7
// 2271.644 us; speedup vs baseline: 1.7976x; 1.5922x over previous
//
#include <hip/hip_runtime.h>
#include <hip/hip_bf16.h>

#define N_VOX 150000
#define CH 32
#define KVOL 27
#define NCLS 20
#define TOT (KVOL * N_VOX)          // 4,050,000
#define MPAD 150016                 // 586*256
#define NPART 586
#define WG_U32 (KVOL * 512)         // 13824 u32 per prepped weight set

#define WSYNC() asm volatile("s_waitcnt lgkmcnt(0)" ::: "memory")

__device__ __forceinline__ unsigned int pk_bf16(float a, float b) {
  unsigned int ua = __float_as_uint(a), ub = __float_as_uint(b);
  ua = ua + 0x7FFFu + ((ua >> 16) & 1u);     // RNE
  ub = ub + 0x7FFFu + ((ub >> 16) & 1u);
  return (ub & 0xFFFF0000u) | (ua >> 16);
}
__device__ __forceinline__ float bf_lo(unsigned int u) { return __uint_as_float(u << 16); }
__device__ __forceinline__ float bf_hi(unsigned int u) { return __uint_as_float(u & 0xFFFF0000u); }

// ==================== build: row-keyed CSR (A and B fused via grid.z) =======

__global__ __launch_bounds__(256) void k_hist(const int* __restrict__ sa,
                                              const int* __restrict__ sb,
                                              int* __restrict__ cnt2) {
  int e = blockIdx.x * 256 + threadIdx.x;
  if (e >= TOT) return;
  const int* s_ = blockIdx.z ? sb : sa;
  atomicAdd(&cnt2[blockIdx.z * MPAD + s_[e]], 1);
}

__global__ __launch_bounds__(256) void k_scan1(const int* __restrict__ cnt2,
                                               int* __restrict__ tmp,
                                               int* __restrict__ part) {
  __shared__ int sbuf[256];
  int t = threadIdx.x;
  int gt = blockIdx.y * MPAD + blockIdx.x * 256 + t;
  int v = cnt2[gt];
  sbuf[t] = v;
  __syncthreads();
  for (int s = 1; s < 256; s <<= 1) {
    int a = (t >= s) ? sbuf[t - s] : 0;
    __syncthreads();
    sbuf[t] += a;
    __syncthreads();
  }
  tmp[gt] = sbuf[t] - v;
  if (t == 255) part[blockIdx.y * 1024 + blockIdx.x] = sbuf[t];
}

__global__ __launch_bounds__(1024) void k_scan2(int* __restrict__ part) {
  __shared__ int sbuf[1024];
  int t = threadIdx.x;
  int* p = part + blockIdx.x * 1024;
  int v = (t < NPART) ? p[t] : 0;
  sbuf[t] = v;
  __syncthreads();
  for (int s = 1; s < 1024; s <<= 1) {
    int a = (t >= s) ? sbuf[t - s] : 0;
    __syncthreads();
    sbuf[t] += a;
    __syncthreads();
  }
  if (t < NPART) p[t] = sbuf[t] - v;
}

__global__ __launch_bounds__(256) void k_scan3(const int* __restrict__ tmp,
                                               const int* __restrict__ part,
                                               int* __restrict__ off2) {
  int gt = blockIdx.y * MPAD + blockIdx.x * 256 + threadIdx.x;
  off2[gt] = tmp[gt] + part[blockIdx.y * 1024 + blockIdx.x];
}

// fill uses atomicSub on the hist counts (no second memset needed)
__global__ __launch_bounds__(256) void k_fill(
    const int* __restrict__ ga, const int* __restrict__ sa,
    const int* __restrict__ gb, const int* __restrict__ sb,
    const int* __restrict__ off2, int* __restrict__ cnt2,
    unsigned int* __restrict__ plA, unsigned int* __restrict__ plB) {
  int e = blockIdx.x * 256 + threadIdx.x;
  if (e >= TOT) return;
  int z = blockIdx.z;
  const int* s_ = z ? sb : sa;
  const int* g_ = z ? gb : ga;
  unsigned int* pl = z ? plB : plA;
  int k = e / N_VOX;                    // compiler magic-div
  int sv = s_[e];
  int q = z * MPAD + sv;
  int pos = atomicSub(&cnt2[q], 1) - 1;
  pl[off2[q] + pos] = ((unsigned int)g_[e] << 5) | (unsigned int)k;
}

// ==================== weight prep: [k][cin][16 cout-pairs] bf16 =============
__global__ __launch_bounds__(256) void k_wprep(const float* __restrict__ W,
                                               unsigned int* __restrict__ out) {
  int i = blockIdx.x * 256 + threadIdx.x;
  if (i >= WG_U32) return;
  int k = i >> 9, r = i & 511, cin = r >> 4, p = r & 15;
  const float* wk = W + k * 1024 + cin * 32 + p * 2;
  out[i] = pk_bf16(wk[0], wk[1]);
}

// ==================== f32 -> bf16 activation convert ========================
__global__ __launch_bounds__(256) void k_tobf(const float4* __restrict__ in4,
                                              uint4* __restrict__ out4) {
  int i = blockIdx.x * 256 + threadIdx.x;
  if (i >= (N_VOX * CH) / 8) return;
  float4 f0 = in4[i * 2], f1 = in4[i * 2 + 1];
  uint4 o;
  o.x = pk_bf16(f0.x, f0.y); o.y = pk_bf16(f0.z, f0.w);
  o.z = pk_bf16(f1.x, f1.y); o.w = pk_bf16(f1.z, f1.w);
  out4[i] = o;
}

// ==================== vector-FMA conv kernel ================================
// Block 256 = 32 groups of 8 lanes; group owns ONE output row; its CSR
// entries are contiguous. Per entry, lane j: 2x b32 gather (one 64B line,
// cins {2j,2j+1,16+2j,17+2j}), W from LDS (bf16 pairs, stride 20), 128 FMA
// into acc[32]. Butterfly shfl_xor reduce over the 8 lanes, fused
// bias+ReLU+bf16 pack, coalesced 8B/lane row write. No atomics anywhere.

#define ENT_LOAD(S, E) \
  unsigned int p##S = pl[(E)]; \
  unsigned int gi##S = p##S >> 5; \
  int kk##S = (int)(p##S & 31u); \
  unsigned int xa##S = srcU[gi##S * 16 + j]; \
  unsigned int xb##S = srcU[gi##S * 16 + 8 + j];

#define ENT_FMA(S) { \
  const unsigned int* wb_ = sW + kk##S * 640 + j * 40; \
  float x0_ = bf_lo(xa##S), x1_ = bf_hi(xa##S); \
  float x2_ = bf_lo(xb##S), x3_ = bf_hi(xb##S); \
  _Pragma("unroll") for (int q4 = 0; q4 < 4; q4++) { \
    uint4 wA_ = *(const uint4*)(wb_ + 4 * q4); \
    uint4 wB_ = *(const uint4*)(wb_ + 20 + 4 * q4); \
    uint4 wC_ = *(const uint4*)(wb_ + 320 + 4 * q4); \
    uint4 wD_ = *(const uint4*)(wb_ + 340 + 4 * q4); \
    unsigned int uA_[4] = {wA_.x, wA_.y, wA_.z, wA_.w}; \
    unsigned int uB_[4] = {wB_.x, wB_.y, wB_.z, wB_.w}; \
    unsigned int uC_[4] = {wC_.x, wC_.y, wC_.z, wC_.w}; \
    unsigned int uD_[4] = {wD_.x, wD_.y, wD_.z, wD_.w}; \
    _Pragma("unroll") for (int t = 0; t < 4; t++) { \
      int c0_ = 8 * q4 + 2 * t; \
      acc[c0_]     = fmaf(x0_, bf_lo(uA_[t]), acc[c0_]); \
      acc[c0_]     = fmaf(x1_, bf_lo(uB_[t]), acc[c0_]); \
      acc[c0_]     = fmaf(x2_, bf_lo(uC_[t]), acc[c0_]); \
      acc[c0_]     = fmaf(x3_, bf_lo(uD_[t]), acc[c0_]); \
      acc[c0_ + 1] = fmaf(x0_, bf_hi(uA_[t]), acc[c0_ + 1]); \
      acc[c0_ + 1] = fmaf(x1_, bf_hi(uB_[t]), acc[c0_ + 1]); \
      acc[c0_ + 1] = fmaf(x2_, bf_hi(uC_[t]), acc[c0_ + 1]); \
      acc[c0_ + 1] = fmaf(x3_, bf_hi(uD_[t]), acc[c0_ + 1]); \
    } } }

__global__ __launch_bounds__(256, 2) void k_conv(
    const unsigned int* __restrict__ srcU, unsigned int* __restrict__ dstU,
    const int* __restrict__ off, const unsigned int* __restrict__ pl,
    const unsigned int* __restrict__ Wg, const float* __restrict__ bias) {
  __shared__ unsigned int sW[KVOL * 640];   // [k][cin][20] u32, 69120 B
  __shared__ float sB[CH];

  const int tid = threadIdx.x;
  for (int i = tid; i < KVOL * 512; i += 256) {
    int k = i >> 9, r = i & 511;
    sW[k * 640 + (r >> 4) * 20 + (r & 15)] = Wg[i];
  }
  if (tid < CH) sB[tid] = bias[tid];
  __syncthreads();

  const int g = tid >> 3, j = tid & 7;
  const int row = blockIdx.x * 32 + g;
  int beg = 0, ee = 0;
  if (row < N_VOX) { beg = off[row]; ee = off[row + 1]; }

  float acc[CH];
#pragma unroll
  for (int t = 0; t < CH; t++) acc[t] = 0.f;

  int e = beg;
  for (; e + 2 <= ee; e += 2) {
    ENT_LOAD(0, e)
    ENT_LOAD(1, e + 1)
    ENT_FMA(0)
    ENT_FMA(1)
  }
  if (e < ee) {
    ENT_LOAD(2, e)
    ENT_FMA(2)
  }

  // butterfly reduce across the 8 lanes of the group
#pragma unroll
  for (int m = 1; m <= 4; m <<= 1) {
#pragma unroll
    for (int t = 0; t < CH; t++) acc[t] += __shfl_xor(acc[t], m);
  }

  if (row < N_VOX) {
    unsigned int w0 = 0, w1 = 0;
#pragma unroll
    for (int t = 0; t < 16; t++) {
      float lo = fmaxf(acc[2 * t] + sB[2 * t], 0.f);
      float hi = fmaxf(acc[2 * t + 1] + sB[2 * t + 1], 0.f);
      unsigned int pk = pk_bf16(lo, hi);
      if ((t >> 1) == j) { if (t & 1) w1 = pk; else w0 = pk; }
    }
    uint2 o = {w0, w1};
    *(uint2*)(dstU + row * 16 + j * 2) = o;
  }
}

// ==================== logits kernel (bf16 inputs) ===========================
__global__ __launch_bounds__(256) void k_logits(
    const uint4* __restrict__ A4, const uint4* __restrict__ B4,
    const float* __restrict__ Wl, const float* __restrict__ bl,
    float* __restrict__ out) {
  __shared__ float sWl[CH * NCLS];
  __shared__ float sbl[NCLS];
  int tid = threadIdx.x;
  if (tid < CH * NCLS / 4) ((float4*)sWl)[tid] = ((const float4*)Wl)[tid];
  if (tid < NCLS) sbl[tid] = bl[tid];
  __syncthreads();
  int row = blockIdx.x * 256 + tid;
  if (row >= N_VOX) return;
  float acc[NCLS];
#pragma unroll
  for (int jj = 0; jj < NCLS; jj++) acc[jj] = sbl[jj];
#pragma unroll
  for (int q = 0; q < 4; q++) {
    uint4 a = A4[row * 4 + q], b = B4[row * 4 + q];
    unsigned int au[4] = {a.x, a.y, a.z, a.w}, bu[4] = {b.x, b.y, b.z, b.w};
#pragma unroll
    for (int t = 0; t < 4; t++) {
      int c = (q << 3) + (t << 1);
      float x0 = bf_lo(au[t]) + bf_lo(bu[t]);
      float x1 = bf_hi(au[t]) + bf_hi(bu[t]);
#pragma unroll
      for (int jj = 0; jj < NCLS; jj++) {
        acc[jj] = fmaf(x0, sWl[c * NCLS + jj], acc[jj]);
        acc[jj] = fmaf(x1, sWl[(c + 1) * NCLS + jj], acc[jj]);
      }
    }
  }
  float4* op = (float4*)(out + row * NCLS);
#pragma unroll
  for (int j5 = 0; j5 < NCLS / 4; j5++) {
    float4 v = {acc[j5 * 4], acc[j5 * 4 + 1], acc[j5 * 4 + 2], acc[j5 * 4 + 3]};
    op[j5] = v;
  }
}

// ==================== launch ================================================
extern "C" void kernel_launch(void* const* d_in, const int* in_sizes, int n_in,
                              void* d_out, int out_size, void* d_ws, size_t ws_size,
                              hipStream_t stream) {
  const float* in_feats = (const float*)d_in[0];
  const int*   ga       = (const int*)d_in[1];
  const int*   sa       = (const int*)d_in[2];
  const int*   gb       = (const int*)d_in[3];
  const int*   sb       = (const int*)d_in[4];
  const float* w1       = (const float*)d_in[5];
  const float* b1       = (const float*)d_in[6];
  const float* w1_2     = (const float*)d_in[7];
  const float* b1_2     = (const float*)d_in[8];
  const float* w2       = (const float*)d_in[9];
  const float* b2       = (const float*)d_in[10];
  const float* w3       = (const float*)d_in[11];
  const float* b3       = (const float*)d_in[12];
  const float* wl       = (const float*)d_in[13];
  const float* bl       = (const float*)d_in[14];
  float* out = (float*)d_out;

  // ---- workspace carve-up (u32 units, ~74 MB) ----
  unsigned int* wsu = (unsigned int*)d_ws;
  size_t o = 0;
  unsigned int* bufA = wsu + o; o += (size_t)MPAD * 16;
  unsigned int* bufB = wsu + o; o += (size_t)MPAD * 16;
  unsigned int* bufC = wsu + o; o += (size_t)MPAD * 16;
  unsigned int* inbf = wsu + o; o += (size_t)MPAD * 16;
  unsigned int* Wg1   = wsu + o; o += WG_U32;
  unsigned int* Wg1_2 = wsu + o; o += WG_U32;
  unsigned int* Wg2   = wsu + o; o += WG_U32;
  unsigned int* Wg3   = wsu + o; o += WG_U32;
  int* off2 = (int*)(wsu + o); o += 2 * MPAD;
  int* cnt2 = (int*)(wsu + o); o += 2 * MPAD;
  int* tmp  = (int*)(wsu + o); o += 2 * MPAD;
  int* part = (int*)(wsu + o); o += 2048;
  unsigned int* plA = wsu + o; o += TOT;
  unsigned int* plB = wsu + o; o += TOT;

  dim3 blk(256);
  dim3 gT((TOT + 255) / 256, 1, 2);          // 15821 x 2
  dim3 gS1(NPART, 2);
  const int g_conv = MPAD / 32;              // 4688
  const int g_wp   = (WG_U32 + 255) / 256;   // 54
  const int g_bf   = 2344;
  const int g_lg   = (N_VOX + 255) / 256;

  // ---- build row-keyed CSRs (A and B in one pass each) ----
  hipMemsetAsync(cnt2, 0, 2 * (size_t)MPAD * sizeof(int), stream);
  k_hist<<<gT, blk, 0, stream>>>(sa, sb, cnt2);
  k_scan1<<<gS1, blk, 0, stream>>>(cnt2, tmp, part);
  k_scan2<<<dim3(2), dim3(1024), 0, stream>>>(part);
  k_scan3<<<gS1, blk, 0, stream>>>(tmp, part, off2);
  k_fill<<<gT, blk, 0, stream>>>(ga, sa, gb, sb, off2, cnt2, plA, plB);

  // ---- weight prep + activation convert ----
  k_wprep<<<g_wp, blk, 0, stream>>>(w1,   Wg1);
  k_wprep<<<g_wp, blk, 0, stream>>>(w1_2, Wg1_2);
  k_wprep<<<g_wp, blk, 0, stream>>>(w2,   Wg2);
  k_wprep<<<g_wp, blk, 0, stream>>>(w3,   Wg3);
  k_tobf<<<g_bf, blk, 0, stream>>>((const float4*)in_feats, (uint4*)inbf);

  // ---- 4 conv layers (row-parallel, no atomics) ----
  const int* offA = off2;
  const int* offB = off2 + MPAD;
  k_conv<<<g_conv, blk, 0, stream>>>(inbf, bufA, offA, plA, Wg1, b1);
  k_conv<<<g_conv, blk, 0, stream>>>(bufA, bufB, offB, plB, Wg1_2, b1_2);
  k_conv<<<g_conv, blk, 0, stream>>>(inbf, bufC, offB, plB, Wg2, b2);
  k_conv<<<g_conv, blk, 0, stream>>>(bufC, bufA, offA, plA, Wg3, b3);

  // ---- logits ----
  k_logits<<<g_lg, blk, 0, stream>>>((const uint4*)bufB, (const uint4*)bufA,
                                     wl, bl, out);
}

// Round 8
// 1610.213 us; speedup vs baseline: 2.5360x; 1.4108x over previous
//
#include <hip/hip_runtime.h>
#include <hip/hip_bf16.h>

#define N_VOX 150000
#define CH 32
#define KVOL 27
#define NCLS 20
#define TOT (KVOL * N_VOX)          // 4,050,000
#define MPAD 150016                 // 586*256
#define NCB 293                     // coarse buckets (sv>>9), 512 rows each
#define NE1 8192                    // entries per scat block
#define NBLK1 495                   // ceil(TOT/8192)
#define WG_U32 (KVOL * 512)         // 13824 u32 per prepped weight set

__device__ __forceinline__ unsigned int pk_bf16(float a, float b) {
  unsigned int ua = __float_as_uint(a), ub = __float_as_uint(b);
  ua = ua + 0x7FFFu + ((ua >> 16) & 1u);     // RNE
  ub = ub + 0x7FFFu + ((ub >> 16) & 1u);
  return (ub & 0xFFFF0000u) | (ua >> 16);
}
__device__ __forceinline__ float bf_lo(unsigned int u) { return __uint_as_float(u << 16); }
__device__ __forceinline__ float bf_hi(unsigned int u) { return __uint_as_float(u & 0xFFFF0000u); }

// ==================== build: 2-pass counting sort ===========================
// pass 0: count entries per coarse bucket (sv>>9), per rulebook z
__global__ __launch_bounds__(512) void k_c0(const int* __restrict__ sa,
                                            const int* __restrict__ sb,
                                            int* __restrict__ ccnt) {
  __shared__ int h[512];
  const int t = threadIdx.x;
  const int z = blockIdx.z;
  const int* s_ = z ? sb : sa;
  const int e0 = blockIdx.x * NE1;
  h[t] = 0;
  __syncthreads();
#pragma unroll
  for (int i = 0; i < NE1 / 512; i++) {
    int e = e0 + t + i * 512;
    if (e < TOT) atomicAdd(&h[s_[e] >> 9], 1);
  }
  __syncthreads();
  if (h[t]) atomicAdd(&ccnt[z * 512 + t], h[t]);
}

// tiny scan: bucket bases + working cursors (one block per z)
__global__ __launch_bounds__(512) void k_cscan(const int* __restrict__ ccnt,
                                               int* __restrict__ cbase,
                                               int* __restrict__ ccur) {
  __shared__ int sc[512];
  const int t = threadIdx.x;
  const int z = blockIdx.x;
  int v = ccnt[z * 512 + t];
  sc[t] = v;
  __syncthreads();
  for (int s = 1; s < 512; s <<= 1) {
    int a = (t >= s) ? sc[t - s] : 0;
    __syncthreads();
    sc[t] += a;
    __syncthreads();
  }
  int excl = sc[t] - v;
  cbase[z * 512 + t] = excl;
  ccur[z * 512 + t] = excl;
}

// pass 1: scatter entries into coarse-bucket regions of tmp.
// payload = (sv&511)<<23 | gi<<5 | k  (9+18+5 = 32 bits)
__global__ __launch_bounds__(512) void k_scat(const int* __restrict__ s_,
                                              const int* __restrict__ g_,
                                              int* __restrict__ ccur,
                                              unsigned int* __restrict__ tmp,
                                              int z) {
  __shared__ int h[512], lb[512], lc[512];
  const int t = threadIdx.x;
  const int e0 = blockIdx.x * NE1;
  h[t] = 0;
  __syncthreads();
#pragma unroll
  for (int i = 0; i < NE1 / 512; i++) {
    int e = e0 + t + i * 512;
    if (e < TOT) atomicAdd(&h[s_[e] >> 9], 1);
  }
  __syncthreads();
  lb[t] = h[t] ? atomicAdd(&ccur[z * 512 + t], h[t]) : 0;
  lc[t] = 0;
  __syncthreads();
#pragma unroll
  for (int i = 0; i < NE1 / 512; i++) {
    int e = e0 + t + i * 512;
    if (e < TOT) {
      int sv = s_[e];
      int bk = sv >> 9;
      int k = e / N_VOX;                       // compiler magic-div
      unsigned int p = ((unsigned int)(sv & 511) << 23) |
                       ((unsigned int)g_[e] << 5) | (unsigned int)k;
      int pos = lb[bk] + atomicAdd(&lc[bk], 1);
      tmp[pos] = p;
    }
  }
}

// pass 2: one block per coarse bucket: local 512-bin hist+scan -> off2 + final pl
__global__ __launch_bounds__(512) void k_p2(const unsigned int* __restrict__ tmp,
                                            const int* __restrict__ cbase,
                                            int* __restrict__ off2,
                                            unsigned int* __restrict__ pl,
                                            int z) {
  __shared__ int h[512], sc[512], lc[512];
  const int t = threadIdx.x;
  const int b = blockIdx.x;
  const int rb = cbase[z * 512 + b];
  const int re = cbase[z * 512 + b + 1];
  h[t] = 0;
  __syncthreads();
  for (int i = rb + t; i < re; i += 512) atomicAdd(&h[tmp[i] >> 23], 1);
  __syncthreads();
  sc[t] = h[t];
  __syncthreads();
  for (int s = 1; s < 512; s <<= 1) {
    int a = (t >= s) ? sc[t - s] : 0;
    __syncthreads();
    sc[t] += a;
    __syncthreads();
  }
  int excl = sc[t] - h[t];
  off2[z * MPAD + b * 512 + t] = rb + excl;
  lc[t] = excl;
  __syncthreads();
  for (int i = rb + t; i < re; i += 512) {
    unsigned int p = tmp[i];
    int bin = (int)(p >> 23);
    int pos = rb + atomicAdd(&lc[bin], 1);
    pl[pos] = p & 0x7FFFFFu;
  }
}

// ==================== weight prep: [k][cin][16 cout-pairs] bf16 =============
__global__ __launch_bounds__(256) void k_wprep(const float* __restrict__ W,
                                               unsigned int* __restrict__ out) {
  int i = blockIdx.x * 256 + threadIdx.x;
  if (i >= WG_U32) return;
  int k = i >> 9, r = i & 511, cin = r >> 4, p = r & 15;
  const float* wk = W + k * 1024 + cin * 32 + p * 2;
  out[i] = pk_bf16(wk[0], wk[1]);
}

// ==================== f32 -> bf16 activation convert ========================
__global__ __launch_bounds__(256) void k_tobf(const float4* __restrict__ in4,
                                              uint4* __restrict__ out4) {
  int i = blockIdx.x * 256 + threadIdx.x;
  if (i >= (N_VOX * CH) / 8) return;
  float4 f0 = in4[i * 2], f1 = in4[i * 2 + 1];
  uint4 o;
  o.x = pk_bf16(f0.x, f0.y); o.y = pk_bf16(f0.z, f0.w);
  o.z = pk_bf16(f1.x, f1.y); o.w = pk_bf16(f1.z, f1.w);
  out4[i] = o;
}

// ==================== vector-FMA conv kernel (round-7, unchanged) ===========
#define ENT_LOAD(S, E) \
  unsigned int p##S = pl[(E)]; \
  unsigned int gi##S = p##S >> 5; \
  int kk##S = (int)(p##S & 31u); \
  unsigned int xa##S = srcU[gi##S * 16 + j]; \
  unsigned int xb##S = srcU[gi##S * 16 + 8 + j];

#define ENT_FMA(S) { \
  const unsigned int* wb_ = sW + kk##S * 640 + j * 40; \
  float x0_ = bf_lo(xa##S), x1_ = bf_hi(xa##S); \
  float x2_ = bf_lo(xb##S), x3_ = bf_hi(xb##S); \
  _Pragma("unroll") for (int q4 = 0; q4 < 4; q4++) { \
    uint4 wA_ = *(const uint4*)(wb_ + 4 * q4); \
    uint4 wB_ = *(const uint4*)(wb_ + 20 + 4 * q4); \
    uint4 wC_ = *(const uint4*)(wb_ + 320 + 4 * q4); \
    uint4 wD_ = *(const uint4*)(wb_ + 340 + 4 * q4); \
    unsigned int uA_[4] = {wA_.x, wA_.y, wA_.z, wA_.w}; \
    unsigned int uB_[4] = {wB_.x, wB_.y, wB_.z, wB_.w}; \
    unsigned int uC_[4] = {wC_.x, wC_.y, wC_.z, wC_.w}; \
    unsigned int uD_[4] = {wD_.x, wD_.y, wD_.z, wD_.w}; \
    _Pragma("unroll") for (int t = 0; t < 4; t++) { \
      int c0_ = 8 * q4 + 2 * t; \
      acc[c0_]     = fmaf(x0_, bf_lo(uA_[t]), acc[c0_]); \
      acc[c0_]     = fmaf(x1_, bf_lo(uB_[t]), acc[c0_]); \
      acc[c0_]     = fmaf(x2_, bf_lo(uC_[t]), acc[c0_]); \
      acc[c0_]     = fmaf(x3_, bf_lo(uD_[t]), acc[c0_]); \
      acc[c0_ + 1] = fmaf(x0_, bf_hi(uA_[t]), acc[c0_ + 1]); \
      acc[c0_ + 1] = fmaf(x1_, bf_hi(uB_[t]), acc[c0_ + 1]); \
      acc[c0_ + 1] = fmaf(x2_, bf_hi(uC_[t]), acc[c0_ + 1]); \
      acc[c0_ + 1] = fmaf(x3_, bf_hi(uD_[t]), acc[c0_ + 1]); \
    } } }

__global__ __launch_bounds__(256, 2) void k_conv(
    const unsigned int* __restrict__ srcU, unsigned int* __restrict__ dstU,
    const int* __restrict__ off, const unsigned int* __restrict__ pl,
    const unsigned int* __restrict__ Wg, const float* __restrict__ bias) {
  __shared__ unsigned int sW[KVOL * 640];   // [k][cin][20] u32, 69120 B
  __shared__ float sB[CH];

  const int tid = threadIdx.x;
  for (int i = tid; i < KVOL * 512; i += 256) {
    int k = i >> 9, r = i & 511;
    sW[k * 640 + (r >> 4) * 20 + (r & 15)] = Wg[i];
  }
  if (tid < CH) sB[tid] = bias[tid];
  __syncthreads();

  const int g = tid >> 3, j = tid & 7;
  const int row = blockIdx.x * 32 + g;
  int beg = 0, ee = 0;
  if (row < N_VOX) { beg = off[row]; ee = off[row + 1]; }

  float acc[CH];
#pragma unroll
  for (int t = 0; t < CH; t++) acc[t] = 0.f;

  int e = beg;
  for (; e + 2 <= ee; e += 2) {
    ENT_LOAD(0, e)
    ENT_LOAD(1, e + 1)
    ENT_FMA(0)
    ENT_FMA(1)
  }
  if (e < ee) {
    ENT_LOAD(2, e)
    ENT_FMA(2)
  }

#pragma unroll
  for (int m = 1; m <= 4; m <<= 1) {
#pragma unroll
    for (int t = 0; t < CH; t++) acc[t] += __shfl_xor(acc[t], m);
  }

  if (row < N_VOX) {
    unsigned int w0 = 0, w1 = 0;
#pragma unroll
    for (int t = 0; t < 16; t++) {
      float lo = fmaxf(acc[2 * t] + sB[2 * t], 0.f);
      float hi = fmaxf(acc[2 * t + 1] + sB[2 * t + 1], 0.f);
      unsigned int pk = pk_bf16(lo, hi);
      if ((t >> 1) == j) { if (t & 1) w1 = pk; else w0 = pk; }
    }
    uint2 o = {w0, w1};
    *(uint2*)(dstU + row * 16 + j * 2) = o;
  }
}

// ==================== logits kernel (bf16 inputs) ===========================
__global__ __launch_bounds__(256) void k_logits(
    const uint4* __restrict__ A4, const uint4* __restrict__ B4,
    const float* __restrict__ Wl, const float* __restrict__ bl,
    float* __restrict__ out) {
  __shared__ float sWl[CH * NCLS];
  __shared__ float sbl[NCLS];
  int tid = threadIdx.x;
  if (tid < CH * NCLS / 4) ((float4*)sWl)[tid] = ((const float4*)Wl)[tid];
  if (tid < NCLS) sbl[tid] = bl[tid];
  __syncthreads();
  int row = blockIdx.x * 256 + tid;
  if (row >= N_VOX) return;
  float acc[NCLS];
#pragma unroll
  for (int jj = 0; jj < NCLS; jj++) acc[jj] = sbl[jj];
#pragma unroll
  for (int q = 0; q < 4; q++) {
    uint4 a = A4[row * 4 + q], b = B4[row * 4 + q];
    unsigned int au[4] = {a.x, a.y, a.z, a.w}, bu[4] = {b.x, b.y, b.z, b.w};
#pragma unroll
    for (int t = 0; t < 4; t++) {
      int c = (q << 3) + (t << 1);
      float x0 = bf_lo(au[t]) + bf_lo(bu[t]);
      float x1 = bf_hi(au[t]) + bf_hi(bu[t]);
#pragma unroll
      for (int jj = 0; jj < NCLS; jj++) {
        acc[jj] = fmaf(x0, sWl[c * NCLS + jj], acc[jj]);
        acc[jj] = fmaf(x1, sWl[(c + 1) * NCLS + jj], acc[jj]);
      }
    }
  }
  float4* op = (float4*)(out + row * NCLS);
#pragma unroll
  for (int j5 = 0; j5 < NCLS / 4; j5++) {
    float4 v = {acc[j5 * 4], acc[j5 * 4 + 1], acc[j5 * 4 + 2], acc[j5 * 4 + 3]};
    op[j5] = v;
  }
}

// ==================== launch ================================================
extern "C" void kernel_launch(void* const* d_in, const int* in_sizes, int n_in,
                              void* d_out, int out_size, void* d_ws, size_t ws_size,
                              hipStream_t stream) {
  const float* in_feats = (const float*)d_in[0];
  const int*   ga       = (const int*)d_in[1];
  const int*   sa       = (const int*)d_in[2];
  const int*   gb       = (const int*)d_in[3];
  const int*   sb       = (const int*)d_in[4];
  const float* w1       = (const float*)d_in[5];
  const float* b1       = (const float*)d_in[6];
  const float* w1_2     = (const float*)d_in[7];
  const float* b1_2     = (const float*)d_in[8];
  const float* w2       = (const float*)d_in[9];
  const float* b2       = (const float*)d_in[10];
  const float* w3       = (const float*)d_in[11];
  const float* b3       = (const float*)d_in[12];
  const float* wl       = (const float*)d_in[13];
  const float* bl       = (const float*)d_in[14];
  float* out = (float*)d_out;

  // ---- workspace carve-up (u32 units, ~88.4 MB) ----
  unsigned int* wsu = (unsigned int*)d_ws;
  size_t o = 0;
  unsigned int* bufA = wsu + o; o += (size_t)MPAD * 16;
  unsigned int* bufB = wsu + o; o += (size_t)MPAD * 16;
  unsigned int* bufC = wsu + o; o += (size_t)MPAD * 16;
  unsigned int* inbf = wsu + o; o += (size_t)MPAD * 16;
  unsigned int* Wg1   = wsu + o; o += WG_U32;
  unsigned int* Wg1_2 = wsu + o; o += WG_U32;
  unsigned int* Wg2   = wsu + o; o += WG_U32;
  unsigned int* Wg3   = wsu + o; o += WG_U32;
  int* off2  = (int*)(wsu + o); o += 2 * MPAD;
  int* ccnt  = (int*)(wsu + o); o += 1024;
  int* cbase = (int*)(wsu + o); o += 1024;
  int* ccur  = (int*)(wsu + o); o += 1024;
  unsigned int* tmp = wsu + o; o += TOT;
  unsigned int* plA = wsu + o; o += TOT;
  unsigned int* plB = wsu + o; o += TOT;

  dim3 blk(256);
  const int g_conv = MPAD / 32;              // 4688
  const int g_wp   = (WG_U32 + 255) / 256;   // 54
  const int g_bf   = 2344;
  const int g_lg   = (N_VOX + 255) / 256;

  // ---- build row-keyed CSRs via 2-pass counting sort ----
  hipMemsetAsync(ccnt, 0, 1024 * sizeof(int), stream);
  k_c0<<<dim3(NBLK1, 1, 2), dim3(512), 0, stream>>>(sa, sb, ccnt);
  k_cscan<<<2, dim3(512), 0, stream>>>(ccnt, cbase, ccur);
  k_scat<<<NBLK1, dim3(512), 0, stream>>>(sa, ga, ccur, tmp, 0);
  k_p2<<<NCB, dim3(512), 0, stream>>>(tmp, cbase, off2, plA, 0);
  k_scat<<<NBLK1, dim3(512), 0, stream>>>(sb, gb, ccur, tmp, 1);
  k_p2<<<NCB, dim3(512), 0, stream>>>(tmp, cbase, off2, plB, 1);

  // ---- weight prep + activation convert ----
  k_wprep<<<g_wp, blk, 0, stream>>>(w1,   Wg1);
  k_wprep<<<g_wp, blk, 0, stream>>>(w1_2, Wg1_2);
  k_wprep<<<g_wp, blk, 0, stream>>>(w2,   Wg2);
  k_wprep<<<g_wp, blk, 0, stream>>>(w3,   Wg3);
  k_tobf<<<g_bf, blk, 0, stream>>>((const float4*)in_feats, (uint4*)inbf);

  // ---- 4 conv layers (row-parallel, no atomics) ----
  const int* offA = off2;
  const int* offB = off2 + MPAD;
  k_conv<<<g_conv, blk, 0, stream>>>(inbf, bufA, offA, plA, Wg1, b1);
  k_conv<<<g_conv, blk, 0, stream>>>(bufA, bufB, offB, plB, Wg1_2, b1_2);
  k_conv<<<g_conv, blk, 0, stream>>>(inbf, bufC, offB, plB, Wg2, b2);
  k_conv<<<g_conv, blk, 0, stream>>>(bufC, bufA, offA, plA, Wg3, b3);

  // ---- logits ----
  k_logits<<<g_lg, blk, 0, stream>>>((const uint4*)bufB, (const uint4*)bufA,
                                     wl, bl, out);
}

// Round 10
// 1333.451 us; speedup vs baseline: 3.0624x; 1.2076x over previous
//
#include <hip/hip_runtime.h>
#include <hip/hip_bf16.h>

#define N_VOX 150000
#define CH 32
#define KVOL 27
#define NCLS 20
#define TOT (KVOL * N_VOX)          // 4,050,000
#define MPAD 150016                 // 586*256
#define NCB 293                     // coarse buckets (sv>>9), 512 rows each
#define NE1 8192                    // entries per scat block
#define NBLK1 495                   // ceil(TOT/8192)
#define WG_U32 (KVOL * 512)         // 13824 u32 per prepped weight set
#define KSTR 580                    // LDS u32 stride per k (4k mod 32 bank spread)
#define JSTR 36                     // LDS u32 stride per cin-pair (4j bank spread)

typedef _Float16 f16x2 __attribute__((ext_vector_type(2)));
union U32H { unsigned int u; f16x2 h; };

__device__ __forceinline__ unsigned int pk_f16(float a, float b) {
  auto r = __builtin_amdgcn_cvt_pkrtz(a, b);   // __fp16 ext_vector(2)
  unsigned int u;
  __builtin_memcpy(&u, &r, 4);
  return u;
}
__device__ __forceinline__ float f16_lo(unsigned int u) { U32H v; v.u = u; return (float)v.h[0]; }
__device__ __forceinline__ float f16_hi(unsigned int u) { U32H v; v.u = u; return (float)v.h[1]; }

#if __has_builtin(__builtin_amdgcn_fdot2)
#define DOT2(x, w, c) __builtin_amdgcn_fdot2((x), (w), (c), false)
#else
#define DOT2(x, w, c) fmaf((float)(x)[0], (float)(w)[0], fmaf((float)(x)[1], (float)(w)[1], (c)))
#endif

// ==================== build: 2-pass counting sort (round-8, unchanged) ======
__global__ __launch_bounds__(512) void k_c0(const int* __restrict__ sa,
                                            const int* __restrict__ sb,
                                            int* __restrict__ ccnt) {
  __shared__ int h[512];
  const int t = threadIdx.x;
  const int z = blockIdx.z;
  const int* s_ = z ? sb : sa;
  const int e0 = blockIdx.x * NE1;
  h[t] = 0;
  __syncthreads();
#pragma unroll
  for (int i = 0; i < NE1 / 512; i++) {
    int e = e0 + t + i * 512;
    if (e < TOT) atomicAdd(&h[s_[e] >> 9], 1);
  }
  __syncthreads();
  if (h[t]) atomicAdd(&ccnt[z * 512 + t], h[t]);
}

__global__ __launch_bounds__(512) void k_cscan(const int* __restrict__ ccnt,
                                               int* __restrict__ cbase,
                                               int* __restrict__ ccur) {
  __shared__ int sc[512];
  const int t = threadIdx.x;
  const int z = blockIdx.x;
  int v = ccnt[z * 512 + t];
  sc[t] = v;
  __syncthreads();
  for (int s = 1; s < 512; s <<= 1) {
    int a = (t >= s) ? sc[t - s] : 0;
    __syncthreads();
    sc[t] += a;
    __syncthreads();
  }
  int excl = sc[t] - v;
  cbase[z * 512 + t] = excl;
  ccur[z * 512 + t] = excl;
}

__global__ __launch_bounds__(512) void k_scat(const int* __restrict__ s_,
                                              const int* __restrict__ g_,
                                              int* __restrict__ ccur,
                                              unsigned int* __restrict__ tmp,
                                              int z) {
  __shared__ int h[512], lb[512], lc[512];
  const int t = threadIdx.x;
  const int e0 = blockIdx.x * NE1;
  h[t] = 0;
  __syncthreads();
#pragma unroll
  for (int i = 0; i < NE1 / 512; i++) {
    int e = e0 + t + i * 512;
    if (e < TOT) atomicAdd(&h[s_[e] >> 9], 1);
  }
  __syncthreads();
  lb[t] = h[t] ? atomicAdd(&ccur[z * 512 + t], h[t]) : 0;
  lc[t] = 0;
  __syncthreads();
#pragma unroll
  for (int i = 0; i < NE1 / 512; i++) {
    int e = e0 + t + i * 512;
    if (e < TOT) {
      int sv = s_[e];
      int bk = sv >> 9;
      int k = e / N_VOX;
      unsigned int p = ((unsigned int)(sv & 511) << 23) |
                       ((unsigned int)g_[e] << 5) | (unsigned int)k;
      int pos = lb[bk] + atomicAdd(&lc[bk], 1);
      tmp[pos] = p;
    }
  }
}

__global__ __launch_bounds__(512) void k_p2(const unsigned int* __restrict__ tmp,
                                            const int* __restrict__ cbase,
                                            int* __restrict__ off2,
                                            unsigned int* __restrict__ pl,
                                            int z) {
  __shared__ int h[512], sc[512], lc[512];
  const int t = threadIdx.x;
  const int b = blockIdx.x;
  const int rb = cbase[z * 512 + b];
  const int re = cbase[z * 512 + b + 1];
  h[t] = 0;
  __syncthreads();
  for (int i = rb + t; i < re; i += 512) atomicAdd(&h[tmp[i] >> 23], 1);
  __syncthreads();
  sc[t] = h[t];
  __syncthreads();
  for (int s = 1; s < 512; s <<= 1) {
    int a = (t >= s) ? sc[t - s] : 0;
    __syncthreads();
    sc[t] += a;
    __syncthreads();
  }
  int excl = sc[t] - h[t];
  off2[z * MPAD + b * 512 + t] = rb + excl;
  lc[t] = excl;
  __syncthreads();
  for (int i = rb + t; i < re; i += 512) {
    unsigned int p = tmp[i];
    int bin = (int)(p >> 23);
    int pos = rb + atomicAdd(&lc[bin], 1);
    pl[pos] = p & 0x7FFFFFu;
  }
}

// ==================== weight prep: [k][cinpair jj][cout] f16 pairs ==========
// out[k*512 + jj*32 + c] = pack(W[k][2jj][c], W[k][2jj+1][c])
__global__ __launch_bounds__(256) void k_wprep(const float* __restrict__ W,
                                               unsigned int* __restrict__ out) {
  int i = blockIdx.x * 256 + threadIdx.x;
  if (i >= WG_U32) return;
  int k = i >> 9, r = i & 511, jj = r >> 5, c = r & 31;
  const float* wk = W + k * 1024;
  out[i] = pk_f16(wk[(2 * jj) * 32 + c], wk[(2 * jj + 1) * 32 + c]);
}

// ==================== f32 -> f16 activation convert =========================
__global__ __launch_bounds__(256) void k_tof16(const float4* __restrict__ in4,
                                               uint4* __restrict__ out4) {
  int i = blockIdx.x * 256 + threadIdx.x;
  if (i >= (N_VOX * CH) / 8) return;
  float4 f0 = in4[i * 2], f1 = in4[i * 2 + 1];
  uint4 o;
  o.x = pk_f16(f0.x, f0.y); o.y = pk_f16(f0.z, f0.w);
  o.z = pk_f16(f1.x, f1.y); o.w = pk_f16(f1.z, f1.w);
  out4[i] = o;
}

// ==================== dot2 conv kernel ======================================
// Block 256 = 32 groups of 8 lanes; group owns ONE output row (contiguous CSR
// entries). Lane j owns cins 4j..4j+3: one uint2 gather (coalesced 64B/group),
// weights from LDS [k][jj][c] (jj-stride 36, k-stride 580: conflict-free within
// group, 4k-mod-32 spread across groups), 64 v_dot2_f32_f16 per entry-lane.
// Butterfly shfl reduce, fused bias+ReLU+f16 pack, 8B/lane coalesced write.

#define ENT_LOAD(S, E) \
  unsigned int p##S = pl[(E)]; \
  unsigned int gi##S = p##S >> 5; \
  int kk##S = (int)(p##S & 31u); \
  uint2 xv##S = *(const uint2*)(srcU + gi##S * 16 + 2 * j);

#define ENT_DOT(S) { \
  const unsigned int* wb_ = sW + kk##S * KSTR + j * (2 * JSTR); \
  U32H x01_, x23_; x01_.u = xv##S.x; x23_.u = xv##S.y; \
  _Pragma("unroll") for (int q = 0; q < 8; q++) { \
    uint4 wA_ = *(const uint4*)(wb_ + q * 4); \
    uint4 wB_ = *(const uint4*)(wb_ + JSTR + q * 4); \
    U32H a0_, a1_, a2_, a3_, b0_, b1_, b2_, b3_; \
    a0_.u = wA_.x; a1_.u = wA_.y; a2_.u = wA_.z; a3_.u = wA_.w; \
    b0_.u = wB_.x; b1_.u = wB_.y; b2_.u = wB_.z; b3_.u = wB_.w; \
    acc[q * 4 + 0] = DOT2(x01_.h, a0_.h, acc[q * 4 + 0]); \
    acc[q * 4 + 1] = DOT2(x01_.h, a1_.h, acc[q * 4 + 1]); \
    acc[q * 4 + 2] = DOT2(x01_.h, a2_.h, acc[q * 4 + 2]); \
    acc[q * 4 + 3] = DOT2(x01_.h, a3_.h, acc[q * 4 + 3]); \
    acc[q * 4 + 0] = DOT2(x23_.h, b0_.h, acc[q * 4 + 0]); \
    acc[q * 4 + 1] = DOT2(x23_.h, b1_.h, acc[q * 4 + 1]); \
    acc[q * 4 + 2] = DOT2(x23_.h, b2_.h, acc[q * 4 + 2]); \
    acc[q * 4 + 3] = DOT2(x23_.h, b3_.h, acc[q * 4 + 3]); \
  } }

__global__ __launch_bounds__(256, 2) void k_conv(
    const unsigned int* __restrict__ srcU, unsigned int* __restrict__ dstU,
    const int* __restrict__ off, const unsigned int* __restrict__ pl,
    const unsigned int* __restrict__ Wg, const float* __restrict__ bias) {
  __shared__ unsigned int sW[KVOL * KSTR];   // 62640 B
  __shared__ float sB[CH];

  const int tid = threadIdx.x;
  for (int i = tid; i < KVOL * 512; i += 256) {
    int k = i >> 9, r = i & 511;
    sW[k * KSTR + (r >> 5) * JSTR + (r & 31)] = Wg[i];
  }
  if (tid < CH) sB[tid] = bias[tid];
  __syncthreads();

  const int g = tid >> 3, j = tid & 7;
  const int row = blockIdx.x * 32 + g;
  int beg = 0, ee = 0;
  if (row < N_VOX) { beg = off[row]; ee = off[row + 1]; }

  float acc[CH];
#pragma unroll
  for (int t = 0; t < CH; t++) acc[t] = 0.f;

  int e = beg;
  for (; e + 2 <= ee; e += 2) {
    ENT_LOAD(0, e)
    ENT_LOAD(1, e + 1)
    ENT_DOT(0)
    ENT_DOT(1)
  }
  if (e < ee) {
    ENT_LOAD(2, e)
    ENT_DOT(2)
  }

  // butterfly reduce across the 8 lanes of the group
#pragma unroll
  for (int m = 1; m <= 4; m <<= 1) {
#pragma unroll
    for (int t = 0; t < CH; t++) acc[t] += __shfl_xor(acc[t], m);
  }

  if (row < N_VOX) {
    unsigned int w0 = 0, w1 = 0;
#pragma unroll
    for (int t = 0; t < 16; t++) {
      float lo = fmaxf(acc[2 * t] + sB[2 * t], 0.f);
      float hi = fmaxf(acc[2 * t + 1] + sB[2 * t + 1], 0.f);
      unsigned int pk = pk_f16(lo, hi);
      if ((t >> 1) == j) { if (t & 1) w1 = pk; else w0 = pk; }
    }
    uint2 o = {w0, w1};
    *(uint2*)(dstU + row * 16 + j * 2) = o;
  }
}

// ==================== logits kernel (f16 inputs) ============================
__global__ __launch_bounds__(256) void k_logits(
    const uint4* __restrict__ A4, const uint4* __restrict__ B4,
    const float* __restrict__ Wl, const float* __restrict__ bl,
    float* __restrict__ out) {
  __shared__ float sWl[CH * NCLS];
  __shared__ float sbl[NCLS];
  int tid = threadIdx.x;
  if (tid < CH * NCLS / 4) ((float4*)sWl)[tid] = ((const float4*)Wl)[tid];
  if (tid < NCLS) sbl[tid] = bl[tid];
  __syncthreads();
  int row = blockIdx.x * 256 + tid;
  if (row >= N_VOX) return;
  float acc[NCLS];
#pragma unroll
  for (int jj = 0; jj < NCLS; jj++) acc[jj] = sbl[jj];
#pragma unroll
  for (int q = 0; q < 4; q++) {
    uint4 a = A4[row * 4 + q], b = B4[row * 4 + q];
    unsigned int au[4] = {a.x, a.y, a.z, a.w}, bu[4] = {b.x, b.y, b.z, b.w};
#pragma unroll
    for (int t = 0; t < 4; t++) {
      int c = (q << 3) + (t << 1);
      float x0 = f16_lo(au[t]) + f16_lo(bu[t]);
      float x1 = f16_hi(au[t]) + f16_hi(bu[t]);
#pragma unroll
      for (int jj = 0; jj < NCLS; jj++) {
        acc[jj] = fmaf(x0, sWl[c * NCLS + jj], acc[jj]);
        acc[jj] = fmaf(x1, sWl[(c + 1) * NCLS + jj], acc[jj]);
      }
    }
  }
  float4* op = (float4*)(out + row * NCLS);
#pragma unroll
  for (int j5 = 0; j5 < NCLS / 4; j5++) {
    float4 v = {acc[j5 * 4], acc[j5 * 4 + 1], acc[j5 * 4 + 2], acc[j5 * 4 + 3]};
    op[j5] = v;
  }
}

// ==================== launch ================================================
extern "C" void kernel_launch(void* const* d_in, const int* in_sizes, int n_in,
                              void* d_out, int out_size, void* d_ws, size_t ws_size,
                              hipStream_t stream) {
  const float* in_feats = (const float*)d_in[0];
  const int*   ga       = (const int*)d_in[1];
  const int*   sa       = (const int*)d_in[2];
  const int*   gb       = (const int*)d_in[3];
  const int*   sb       = (const int*)d_in[4];
  const float* w1       = (const float*)d_in[5];
  const float* b1       = (const float*)d_in[6];
  const float* w1_2     = (const float*)d_in[7];
  const float* b1_2     = (const float*)d_in[8];
  const float* w2       = (const float*)d_in[9];
  const float* b2       = (const float*)d_in[10];
  const float* w3       = (const float*)d_in[11];
  const float* b3       = (const float*)d_in[12];
  const float* wl       = (const float*)d_in[13];
  const float* bl       = (const float*)d_in[14];
  float* out = (float*)d_out;

  // ---- workspace carve-up (u32 units, ~88.4 MB) ----
  unsigned int* wsu = (unsigned int*)d_ws;
  size_t o = 0;
  unsigned int* bufA = wsu + o; o += (size_t)MPAD * 16;
  unsigned int* bufB = wsu + o; o += (size_t)MPAD * 16;
  unsigned int* bufC = wsu + o; o += (size_t)MPAD * 16;
  unsigned int* inbf = wsu + o; o += (size_t)MPAD * 16;
  unsigned int* Wg1   = wsu + o; o += WG_U32;
  unsigned int* Wg1_2 = wsu + o; o += WG_U32;
  unsigned int* Wg2   = wsu + o; o += WG_U32;
  unsigned int* Wg3   = wsu + o; o += WG_U32;
  int* off2  = (int*)(wsu + o); o += 2 * MPAD;
  int* ccnt  = (int*)(wsu + o); o += 1024;
  int* cbase = (int*)(wsu + o); o += 1024;
  int* ccur  = (int*)(wsu + o); o += 1024;
  unsigned int* tmp = wsu + o; o += TOT;
  unsigned int* plA = wsu + o; o += TOT;
  unsigned int* plB = wsu + o; o += TOT;

  dim3 blk(256);
  const int g_conv = MPAD / 32;              // 4688
  const int g_wp   = (WG_U32 + 255) / 256;   // 54
  const int g_bf   = 2344;
  const int g_lg   = (N_VOX + 255) / 256;

  // ---- build row-keyed CSRs via 2-pass counting sort ----
  (void)hipMemsetAsync(ccnt, 0, 1024 * sizeof(int), stream);
  k_c0<<<dim3(NBLK1, 1, 2), dim3(512), 0, stream>>>(sa, sb, ccnt);
  k_cscan<<<2, dim3(512), 0, stream>>>(ccnt, cbase, ccur);
  k_scat<<<NBLK1, dim3(512), 0, stream>>>(sa, ga, ccur, tmp, 0);
  k_p2<<<NCB, dim3(512), 0, stream>>>(tmp, cbase, off2, plA, 0);
  k_scat<<<NBLK1, dim3(512), 0, stream>>>(sb, gb, ccur, tmp, 1);
  k_p2<<<NCB, dim3(512), 0, stream>>>(tmp, cbase, off2, plB, 1);

  // ---- weight prep + activation convert ----
  k_wprep<<<g_wp, blk, 0, stream>>>(w1,   Wg1);
  k_wprep<<<g_wp, blk, 0, stream>>>(w1_2, Wg1_2);
  k_wprep<<<g_wp, blk, 0, stream>>>(w2,   Wg2);
  k_wprep<<<g_wp, blk, 0, stream>>>(w3,   Wg3);
  k_tof16<<<g_bf, blk, 0, stream>>>((const float4*)in_feats, (uint4*)inbf);

  // ---- 4 conv layers (row-parallel, no atomics) ----
  const int* offA = off2;
  const int* offB = off2 + MPAD;
  k_conv<<<g_conv, blk, 0, stream>>>(inbf, bufA, offA, plA, Wg1, b1);
  k_conv<<<g_conv, blk, 0, stream>>>(bufA, bufB, offB, plB, Wg1_2, b1_2);
  k_conv<<<g_conv, blk, 0, stream>>>(inbf, bufC, offB, plB, Wg2, b2);
  k_conv<<<g_conv, blk, 0, stream>>>(bufC, bufA, offA, plA, Wg3, b3);

  // ---- logits ----
  k_logits<<<g_lg, blk, 0, stream>>>((const uint4*)bufB, (const uint4*)bufA,
                                     wl, bl, out);
}

// Round 11
// 1012.122 us; speedup vs baseline: 4.0346x; 1.3175x over previous
//
#include <hip/hip_runtime.h>
#include <hip/hip_bf16.h>

#define N_VOX 150000
#define CH 32
#define KVOL 27
#define NCLS 20
#define TOT (KVOL * N_VOX)          // 4,050,000
#define MPAD 150016                 // 586*256
#define NCB 293                     // coarse buckets (sv>>9), 512 rows each
#define NE1 8192                    // entries per scat block
#define NBLK1 495                   // ceil(TOT/8192)
#define WG_U32 (KVOL * 512)         // 13824 u32 per prepped weight set
#define KSTR 580                    // LDS u32 stride per k (>=16*JSTR, ==4 mod 32)
#define JSTR 36                     // LDS u32 stride per cin-pair (==4 mod 32)

typedef _Float16 f16x2 __attribute__((ext_vector_type(2)));
union U32H { unsigned int u; f16x2 h; };

__device__ __forceinline__ unsigned int pk_f16(float a, float b) {
  auto r = __builtin_amdgcn_cvt_pkrtz(a, b);   // __fp16 ext_vector(2)
  unsigned int u;
  __builtin_memcpy(&u, &r, 4);
  return u;
}
__device__ __forceinline__ float f16_lo(unsigned int u) { U32H v; v.u = u; return (float)v.h[0]; }
__device__ __forceinline__ float f16_hi(unsigned int u) { U32H v; v.u = u; return (float)v.h[1]; }

#if __has_builtin(__builtin_amdgcn_fdot2)
#define DOT2(x, w, c) __builtin_amdgcn_fdot2((x), (w), (c), false)
#else
#define DOT2(x, w, c) fmaf((float)(x)[0], (float)(w)[0], fmaf((float)(x)[1], (float)(w)[1], (c)))
#endif

// ==================== build: 2-pass counting sort (round-8, unchanged) ======
__global__ __launch_bounds__(512) void k_c0(const int* __restrict__ sa,
                                            const int* __restrict__ sb,
                                            int* __restrict__ ccnt) {
  __shared__ int h[512];
  const int t = threadIdx.x;
  const int z = blockIdx.z;
  const int* s_ = z ? sb : sa;
  const int e0 = blockIdx.x * NE1;
  h[t] = 0;
  __syncthreads();
#pragma unroll
  for (int i = 0; i < NE1 / 512; i++) {
    int e = e0 + t + i * 512;
    if (e < TOT) atomicAdd(&h[s_[e] >> 9], 1);
  }
  __syncthreads();
  if (h[t]) atomicAdd(&ccnt[z * 512 + t], h[t]);
}

__global__ __launch_bounds__(512) void k_cscan(const int* __restrict__ ccnt,
                                               int* __restrict__ cbase,
                                               int* __restrict__ ccur) {
  __shared__ int sc[512];
  const int t = threadIdx.x;
  const int z = blockIdx.x;
  int v = ccnt[z * 512 + t];
  sc[t] = v;
  __syncthreads();
  for (int s = 1; s < 512; s <<= 1) {
    int a = (t >= s) ? sc[t - s] : 0;
    __syncthreads();
    sc[t] += a;
    __syncthreads();
  }
  int excl = sc[t] - v;
  cbase[z * 512 + t] = excl;
  ccur[z * 512 + t] = excl;
}

__global__ __launch_bounds__(512) void k_scat(const int* __restrict__ s_,
                                              const int* __restrict__ g_,
                                              int* __restrict__ ccur,
                                              unsigned int* __restrict__ tmp,
                                              int z) {
  __shared__ int h[512], lb[512], lc[512];
  const int t = threadIdx.x;
  const int e0 = blockIdx.x * NE1;
  h[t] = 0;
  __syncthreads();
#pragma unroll
  for (int i = 0; i < NE1 / 512; i++) {
    int e = e0 + t + i * 512;
    if (e < TOT) atomicAdd(&h[s_[e] >> 9], 1);
  }
  __syncthreads();
  lb[t] = h[t] ? atomicAdd(&ccur[z * 512 + t], h[t]) : 0;
  lc[t] = 0;
  __syncthreads();
#pragma unroll
  for (int i = 0; i < NE1 / 512; i++) {
    int e = e0 + t + i * 512;
    if (e < TOT) {
      int sv = s_[e];
      int bk = sv >> 9;
      int k = e / N_VOX;
      unsigned int p = ((unsigned int)(sv & 511) << 23) |
                       ((unsigned int)g_[e] << 5) | (unsigned int)k;
      int pos = lb[bk] + atomicAdd(&lc[bk], 1);
      tmp[pos] = p;
    }
  }
}

__global__ __launch_bounds__(512) void k_p2(const unsigned int* __restrict__ tmp,
                                            const int* __restrict__ cbase,
                                            int* __restrict__ off2,
                                            unsigned int* __restrict__ pl,
                                            int z) {
  __shared__ int h[512], sc[512], lc[512];
  const int t = threadIdx.x;
  const int b = blockIdx.x;
  const int rb = cbase[z * 512 + b];
  const int re = cbase[z * 512 + b + 1];
  h[t] = 0;
  __syncthreads();
  for (int i = rb + t; i < re; i += 512) atomicAdd(&h[tmp[i] >> 23], 1);
  __syncthreads();
  sc[t] = h[t];
  __syncthreads();
  for (int s = 1; s < 512; s <<= 1) {
    int a = (t >= s) ? sc[t - s] : 0;
    __syncthreads();
    sc[t] += a;
    __syncthreads();
  }
  int excl = sc[t] - h[t];
  off2[z * MPAD + b * 512 + t] = rb + excl;
  lc[t] = excl;
  __syncthreads();
  for (int i = rb + t; i < re; i += 512) {
    unsigned int p = tmp[i];
    int bin = (int)(p >> 23);
    int pos = rb + atomicAdd(&lc[bin], 1);
    pl[pos] = p & 0x7FFFFFu;
  }
}

// ==================== weight prep: [k][cinpair jj][cout] f16 pairs ==========
// out[k*512 + jj*32 + c] = pack(W[k][2jj][c], W[k][2jj+1][c])
__global__ __launch_bounds__(256) void k_wprep(const float* __restrict__ W,
                                               unsigned int* __restrict__ out) {
  int i = blockIdx.x * 256 + threadIdx.x;
  if (i >= WG_U32) return;
  int k = i >> 9, r = i & 511, jj = r >> 5, c = r & 31;
  const float* wk = W + k * 1024;
  out[i] = pk_f16(wk[(2 * jj) * 32 + c], wk[(2 * jj + 1) * 32 + c]);
}

// ==================== f32 -> f16 activation convert =========================
__global__ __launch_bounds__(256) void k_tof16(const float4* __restrict__ in4,
                                               uint4* __restrict__ out4) {
  int i = blockIdx.x * 256 + threadIdx.x;
  if (i >= (N_VOX * CH) / 8) return;
  float4 f0 = in4[i * 2], f1 = in4[i * 2 + 1];
  uint4 o;
  o.x = pk_f16(f0.x, f0.y); o.y = pk_f16(f0.z, f0.w);
  o.z = pk_f16(f1.x, f1.y); o.w = pk_f16(f1.z, f1.w);
  out4[i] = o;
}

// ==================== dot2 conv kernel ======================================
// Block 512 = 64 groups of 8 lanes (2 blocks/CU -> 16 waves/CU). Group owns
// ONE output row (contiguous CSR entries). Lane j owns cin-pair rows {j, j+8}
// (cins 2j,2j+1 and 2j+16,2j+17): base offsets j*36 and (j+8)*36 are both
// == 4j mod 32 -> the 8 lanes cover all 8 bank quads, conflict-free per
// 8-lane phase regardless of k. 64 v_dot2_f32_f16 per entry-lane. Butterfly
// shfl reduce, fused bias+ReLU+f16 pack, 8B/lane coalesced write.

#define ENT_LOAD(S, E) \
  unsigned int p##S = pl[(E)]; \
  unsigned int gi##S = p##S >> 5; \
  int kk##S = (int)(p##S & 31u); \
  unsigned int xa##S = srcU[gi##S * 16 + j]; \
  unsigned int xb##S = srcU[gi##S * 16 + 8 + j];

#define ENT_DOT(S) { \
  const unsigned int* wb_ = sW + kk##S * KSTR + j * JSTR; \
  U32H x01_, x23_; x01_.u = xa##S; x23_.u = xb##S; \
  _Pragma("unroll") for (int q = 0; q < 8; q++) { \
    uint4 wA_ = *(const uint4*)(wb_ + q * 4); \
    uint4 wB_ = *(const uint4*)(wb_ + 8 * JSTR + q * 4); \
    U32H a0_, a1_, a2_, a3_, b0_, b1_, b2_, b3_; \
    a0_.u = wA_.x; a1_.u = wA_.y; a2_.u = wA_.z; a3_.u = wA_.w; \
    b0_.u = wB_.x; b1_.u = wB_.y; b2_.u = wB_.z; b3_.u = wB_.w; \
    acc[q * 4 + 0] = DOT2(x01_.h, a0_.h, acc[q * 4 + 0]); \
    acc[q * 4 + 1] = DOT2(x01_.h, a1_.h, acc[q * 4 + 1]); \
    acc[q * 4 + 2] = DOT2(x01_.h, a2_.h, acc[q * 4 + 2]); \
    acc[q * 4 + 3] = DOT2(x01_.h, a3_.h, acc[q * 4 + 3]); \
    acc[q * 4 + 0] = DOT2(x23_.h, b0_.h, acc[q * 4 + 0]); \
    acc[q * 4 + 1] = DOT2(x23_.h, b1_.h, acc[q * 4 + 1]); \
    acc[q * 4 + 2] = DOT2(x23_.h, b2_.h, acc[q * 4 + 2]); \
    acc[q * 4 + 3] = DOT2(x23_.h, b3_.h, acc[q * 4 + 3]); \
  } }

__global__ __launch_bounds__(512, 2) void k_conv(
    const unsigned int* __restrict__ srcU, unsigned int* __restrict__ dstU,
    const int* __restrict__ off, const unsigned int* __restrict__ pl,
    const unsigned int* __restrict__ Wg, const float* __restrict__ bias) {
  __shared__ unsigned int sW[KVOL * KSTR];   // 62640 B
  __shared__ float sB[CH];

  const int tid = threadIdx.x;
  for (int i = tid; i < KVOL * 512; i += 512) {
    int k = i >> 9, r = i & 511;
    sW[k * KSTR + (r >> 5) * JSTR + (r & 31)] = Wg[i];
  }
  if (tid < CH) sB[tid] = bias[tid];
  __syncthreads();

  const int g = tid >> 3, j = tid & 7;
  const int row = blockIdx.x * 64 + g;
  int beg = 0, ee = 0;
  if (row < N_VOX) { beg = off[row]; ee = off[row + 1]; }

  float acc[CH];
#pragma unroll
  for (int t = 0; t < CH; t++) acc[t] = 0.f;

  int e = beg;
  for (; e + 2 <= ee; e += 2) {
    ENT_LOAD(0, e)
    ENT_LOAD(1, e + 1)
    ENT_DOT(0)
    ENT_DOT(1)
  }
  if (e < ee) {
    ENT_LOAD(2, e)
    ENT_DOT(2)
  }

  // butterfly reduce across the 8 lanes of the group
#pragma unroll
  for (int m = 1; m <= 4; m <<= 1) {
#pragma unroll
    for (int t = 0; t < CH; t++) acc[t] += __shfl_xor(acc[t], m);
  }

  if (row < N_VOX) {
    unsigned int w0 = 0, w1 = 0;
#pragma unroll
    for (int t = 0; t < 16; t++) {
      float lo = fmaxf(acc[2 * t] + sB[2 * t], 0.f);
      float hi = fmaxf(acc[2 * t + 1] + sB[2 * t + 1], 0.f);
      unsigned int pk = pk_f16(lo, hi);
      if ((t >> 1) == j) { if (t & 1) w1 = pk; else w0 = pk; }
    }
    uint2 o = {w0, w1};
    *(uint2*)(dstU + row * 16 + j * 2) = o;
  }
}

// ==================== logits kernel (f16 inputs) ============================
__global__ __launch_bounds__(256) void k_logits(
    const uint4* __restrict__ A4, const uint4* __restrict__ B4,
    const float* __restrict__ Wl, const float* __restrict__ bl,
    float* __restrict__ out) {
  __shared__ float sWl[CH * NCLS];
  __shared__ float sbl[NCLS];
  int tid = threadIdx.x;
  if (tid < CH * NCLS / 4) ((float4*)sWl)[tid] = ((const float4*)Wl)[tid];
  if (tid < NCLS) sbl[tid] = bl[tid];
  __syncthreads();
  int row = blockIdx.x * 256 + tid;
  if (row >= N_VOX) return;
  float acc[NCLS];
#pragma unroll
  for (int jj = 0; jj < NCLS; jj++) acc[jj] = sbl[jj];
#pragma unroll
  for (int q = 0; q < 4; q++) {
    uint4 a = A4[row * 4 + q], b = B4[row * 4 + q];
    unsigned int au[4] = {a.x, a.y, a.z, a.w}, bu[4] = {b.x, b.y, b.z, b.w};
#pragma unroll
    for (int t = 0; t < 4; t++) {
      int c = (q << 3) + (t << 1);
      float x0 = f16_lo(au[t]) + f16_lo(bu[t]);
      float x1 = f16_hi(au[t]) + f16_hi(bu[t]);
#pragma unroll
      for (int jj = 0; jj < NCLS; jj++) {
        acc[jj] = fmaf(x0, sWl[c * NCLS + jj], acc[jj]);
        acc[jj] = fmaf(x1, sWl[(c + 1) * NCLS + jj], acc[jj]);
      }
    }
  }
  float4* op = (float4*)(out + row * NCLS);
#pragma unroll
  for (int j5 = 0; j5 < NCLS / 4; j5++) {
    float4 v = {acc[j5 * 4], acc[j5 * 4 + 1], acc[j5 * 4 + 2], acc[j5 * 4 + 3]};
    op[j5] = v;
  }
}

// ==================== launch ================================================
extern "C" void kernel_launch(void* const* d_in, const int* in_sizes, int n_in,
                              void* d_out, int out_size, void* d_ws, size_t ws_size,
                              hipStream_t stream) {
  const float* in_feats = (const float*)d_in[0];
  const int*   ga       = (const int*)d_in[1];
  const int*   sa       = (const int*)d_in[2];
  const int*   gb       = (const int*)d_in[3];
  const int*   sb       = (const int*)d_in[4];
  const float* w1       = (const float*)d_in[5];
  const float* b1       = (const float*)d_in[6];
  const float* w1_2     = (const float*)d_in[7];
  const float* b1_2     = (const float*)d_in[8];
  const float* w2       = (const float*)d_in[9];
  const float* b2       = (const float*)d_in[10];
  const float* w3       = (const float*)d_in[11];
  const float* b3       = (const float*)d_in[12];
  const float* wl       = (const float*)d_in[13];
  const float* bl       = (const float*)d_in[14];
  float* out = (float*)d_out;

  // ---- workspace carve-up (u32 units, ~88.4 MB) ----
  unsigned int* wsu = (unsigned int*)d_ws;
  size_t o = 0;
  unsigned int* bufA = wsu + o; o += (size_t)MPAD * 16;
  unsigned int* bufB = wsu + o; o += (size_t)MPAD * 16;
  unsigned int* bufC = wsu + o; o += (size_t)MPAD * 16;
  unsigned int* inbf = wsu + o; o += (size_t)MPAD * 16;
  unsigned int* Wg1   = wsu + o; o += WG_U32;
  unsigned int* Wg1_2 = wsu + o; o += WG_U32;
  unsigned int* Wg2   = wsu + o; o += WG_U32;
  unsigned int* Wg3   = wsu + o; o += WG_U32;
  int* off2  = (int*)(wsu + o); o += 2 * MPAD;
  int* ccnt  = (int*)(wsu + o); o += 1024;
  int* cbase = (int*)(wsu + o); o += 1024;
  int* ccur  = (int*)(wsu + o); o += 1024;
  unsigned int* tmp = wsu + o; o += TOT;
  unsigned int* plA = wsu + o; o += TOT;
  unsigned int* plB = wsu + o; o += TOT;

  dim3 blk(256);
  const int g_conv = MPAD / 64;              // 2344 blocks x 512 thr
  const int g_wp   = (WG_U32 + 255) / 256;   // 54
  const int g_bf   = 2344;
  const int g_lg   = (N_VOX + 255) / 256;

  // ---- build row-keyed CSRs via 2-pass counting sort ----
  (void)hipMemsetAsync(ccnt, 0, 1024 * sizeof(int), stream);
  k_c0<<<dim3(NBLK1, 1, 2), dim3(512), 0, stream>>>(sa, sb, ccnt);
  k_cscan<<<2, dim3(512), 0, stream>>>(ccnt, cbase, ccur);
  k_scat<<<NBLK1, dim3(512), 0, stream>>>(sa, ga, ccur, tmp, 0);
  k_p2<<<NCB, dim3(512), 0, stream>>>(tmp, cbase, off2, plA, 0);
  k_scat<<<NBLK1, dim3(512), 0, stream>>>(sb, gb, ccur, tmp, 1);
  k_p2<<<NCB, dim3(512), 0, stream>>>(tmp, cbase, off2, plB, 1);

  // ---- weight prep + activation convert ----
  k_wprep<<<g_wp, blk, 0, stream>>>(w1,   Wg1);
  k_wprep<<<g_wp, blk, 0, stream>>>(w1_2, Wg1_2);
  k_wprep<<<g_wp, blk, 0, stream>>>(w2,   Wg2);
  k_wprep<<<g_wp, blk, 0, stream>>>(w3,   Wg3);
  k_tof16<<<g_bf, blk, 0, stream>>>((const float4*)in_feats, (uint4*)inbf);

  // ---- 4 conv layers (row-parallel, no atomics) ----
  const int* offA = off2;
  const int* offB = off2 + MPAD;
  k_conv<<<g_conv, dim3(512), 0, stream>>>(inbf, bufA, offA, plA, Wg1, b1);
  k_conv<<<g_conv, dim3(512), 0, stream>>>(bufA, bufB, offB, plB, Wg1_2, b1_2);
  k_conv<<<g_conv, dim3(512), 0, stream>>>(inbf, bufC, offB, plB, Wg2, b2);
  k_conv<<<g_conv, dim3(512), 0, stream>>>(bufC, bufA, offA, plA, Wg3, b3);

  // ---- logits ----
  k_logits<<<g_lg, blk, 0, stream>>>((const uint4*)bufB, (const uint4*)bufA,
                                     wl, bl, out);
}

// Round 13
// 925.279 us; speedup vs baseline: 4.4133x; 1.0939x over previous
//
#include <hip/hip_runtime.h>
#include <hip/hip_bf16.h>

#define N_VOX 150000
#define CH 32
#define KVOL 27
#define NCLS 20
#define TOT (KVOL * N_VOX)          // 4,050,000
#define MPAD 150016                 // 586*256
#define NCB 293                     // coarse buckets (sv>>9), 512 rows each
#define NE1 8192                    // entries per scat block
#define NBLK1 495                   // ceil(TOT/8192)
#define WG_U32 (KVOL * 512)         // 13824 u32 per prepped weight set
#define KSTR 576                    // LDS u32 stride per k: >=16*JSTR AND == 0 mod 32
#define JSTR 36                     // LDS u32 stride per cin-pair: == 4 mod 32

typedef _Float16 f16x2 __attribute__((ext_vector_type(2)));
union U32H { unsigned int u; f16x2 h; };

__device__ __forceinline__ unsigned int pk_f16(float a, float b) {
  auto r = __builtin_amdgcn_cvt_pkrtz(a, b);   // __fp16 ext_vector(2)
  unsigned int u;
  __builtin_memcpy(&u, &r, 4);
  return u;
}
__device__ __forceinline__ float f16_lo(unsigned int u) { U32H v; v.u = u; return (float)v.h[0]; }
__device__ __forceinline__ float f16_hi(unsigned int u) { U32H v; v.u = u; return (float)v.h[1]; }

#if __has_builtin(__builtin_amdgcn_fdot2)
#define DOT2(x, w, c) __builtin_amdgcn_fdot2((x), (w), (c), false)
#else
#define DOT2(x, w, c) fmaf((float)(x)[0], (float)(w)[0], fmaf((float)(x)[1], (float)(w)[1], (c)))
#endif

// ==================== build: 2-pass counting sort (unchanged) ===============
__global__ __launch_bounds__(512) void k_c0(const int* __restrict__ sa,
                                            const int* __restrict__ sb,
                                            int* __restrict__ ccnt) {
  __shared__ int h[512];
  const int t = threadIdx.x;
  const int z = blockIdx.z;
  const int* s_ = z ? sb : sa;
  const int e0 = blockIdx.x * NE1;
  h[t] = 0;
  __syncthreads();
#pragma unroll
  for (int i = 0; i < NE1 / 512; i++) {
    int e = e0 + t + i * 512;
    if (e < TOT) atomicAdd(&h[s_[e] >> 9], 1);
  }
  __syncthreads();
  if (h[t]) atomicAdd(&ccnt[z * 512 + t], h[t]);
}

__global__ __launch_bounds__(512) void k_cscan(const int* __restrict__ ccnt,
                                               int* __restrict__ cbase,
                                               int* __restrict__ ccur) {
  __shared__ int sc[512];
  const int t = threadIdx.x;
  const int z = blockIdx.x;
  int v = ccnt[z * 512 + t];
  sc[t] = v;
  __syncthreads();
  for (int s = 1; s < 512; s <<= 1) {
    int a = (t >= s) ? sc[t - s] : 0;
    __syncthreads();
    sc[t] += a;
    __syncthreads();
  }
  int excl = sc[t] - v;
  cbase[z * 512 + t] = excl;
  ccur[z * 512 + t] = excl;
}

__global__ __launch_bounds__(512) void k_scat(const int* __restrict__ s_,
                                              const int* __restrict__ g_,
                                              int* __restrict__ ccur,
                                              unsigned int* __restrict__ tmp,
                                              int z) {
  __shared__ int h[512], lb[512], lc[512];
  const int t = threadIdx.x;
  const int e0 = blockIdx.x * NE1;
  h[t] = 0;
  __syncthreads();
#pragma unroll
  for (int i = 0; i < NE1 / 512; i++) {
    int e = e0 + t + i * 512;
    if (e < TOT) atomicAdd(&h[s_[e] >> 9], 1);
  }
  __syncthreads();
  lb[t] = h[t] ? atomicAdd(&ccur[z * 512 + t], h[t]) : 0;
  lc[t] = 0;
  __syncthreads();
#pragma unroll
  for (int i = 0; i < NE1 / 512; i++) {
    int e = e0 + t + i * 512;
    if (e < TOT) {
      int sv = s_[e];
      int bk = sv >> 9;
      int k = e / N_VOX;
      unsigned int p = ((unsigned int)(sv & 511) << 23) |
                       ((unsigned int)g_[e] << 5) | (unsigned int)k;
      int pos = lb[bk] + atomicAdd(&lc[bk], 1);
      tmp[pos] = p;
    }
  }
}

__global__ __launch_bounds__(512) void k_p2(const unsigned int* __restrict__ tmp,
                                            const int* __restrict__ cbase,
                                            int* __restrict__ off2,
                                            unsigned int* __restrict__ pl,
                                            int z) {
  __shared__ int h[512], sc[512], lc[512];
  const int t = threadIdx.x;
  const int b = blockIdx.x;
  const int rb = cbase[z * 512 + b];
  const int re = cbase[z * 512 + b + 1];
  h[t] = 0;
  __syncthreads();
  for (int i = rb + t; i < re; i += 512) atomicAdd(&h[tmp[i] >> 23], 1);
  __syncthreads();
  sc[t] = h[t];
  __syncthreads();
  for (int s = 1; s < 512; s <<= 1) {
    int a = (t >= s) ? sc[t - s] : 0;
    __syncthreads();
    sc[t] += a;
    __syncthreads();
  }
  int excl = sc[t] - h[t];
  off2[z * MPAD + b * 512 + t] = rb + excl;
  lc[t] = excl;
  __syncthreads();
  for (int i = rb + t; i < re; i += 512) {
    unsigned int p = tmp[i];
    int bin = (int)(p >> 23);
    int pos = rb + atomicAdd(&lc[bin], 1);
    pl[pos] = p & 0x7FFFFFu;
  }
}

// ==================== weight prep: [k][cinpair jj][cout] f16 pairs ==========
__global__ __launch_bounds__(256) void k_wprep(const float* __restrict__ W,
                                               unsigned int* __restrict__ out) {
  int i = blockIdx.x * 256 + threadIdx.x;
  if (i >= WG_U32) return;
  int k = i >> 9, r = i & 511, jj = r >> 5, c = r & 31;
  const float* wk = W + k * 1024;
  out[i] = pk_f16(wk[(2 * jj) * 32 + c], wk[(2 * jj + 1) * 32 + c]);
}

// ==================== f32 -> f16 activation convert =========================
__global__ __launch_bounds__(256) void k_tof16(const float4* __restrict__ in4,
                                               uint4* __restrict__ out4) {
  int i = blockIdx.x * 256 + threadIdx.x;
  if (i >= (N_VOX * CH) / 8) return;
  float4 f0 = in4[i * 2], f1 = in4[i * 2 + 1];
  uint4 o;
  o.x = pk_f16(f0.x, f0.y); o.y = pk_f16(f0.z, f0.w);
  o.z = pk_f16(f1.x, f1.y); o.w = pk_f16(f1.z, f1.w);
  out4[i] = o;
}

// ==================== dot2 conv kernel ======================================
// Block 512 = 64 groups of 8 lanes (2 blocks/CU -> 16 waves/CU). Group owns
// ONE output row (contiguous CSR entries). Lane j owns cin-pair rows {j, j+8}.
// KSTR=576: >= 16*JSTR (no k-block overlap!) and == 0 mod 32 so every k
// presents the identical balanced bank pattern; JSTR == 4 mod 32 so the 8
// lanes of a group cover all 32 banks exactly once per b128 phase. 4-entry
// unroll batches 12 independent global loads per iteration.

#define ENT_LOAD(S, E) \
  unsigned int p##S = pl[(E)]; \
  unsigned int gi##S = p##S >> 5; \
  int kk##S = (int)(p##S & 31u); \
  unsigned int xa##S = srcU[gi##S * 16 + j]; \
  unsigned int xb##S = srcU[gi##S * 16 + 8 + j];

#define ENT_DOT(S) { \
  const unsigned int* wb_ = sW + kk##S * KSTR + j * JSTR; \
  U32H x01_, x23_; x01_.u = xa##S; x23_.u = xb##S; \
  _Pragma("unroll") for (int q = 0; q < 8; q++) { \
    uint4 wA_ = *(const uint4*)(wb_ + q * 4); \
    uint4 wB_ = *(const uint4*)(wb_ + 8 * JSTR + q * 4); \
    U32H a0_, a1_, a2_, a3_, b0_, b1_, b2_, b3_; \
    a0_.u = wA_.x; a1_.u = wA_.y; a2_.u = wA_.z; a3_.u = wA_.w; \
    b0_.u = wB_.x; b1_.u = wB_.y; b2_.u = wB_.z; b3_.u = wB_.w; \
    acc[q * 4 + 0] = DOT2(x01_.h, a0_.h, acc[q * 4 + 0]); \
    acc[q * 4 + 1] = DOT2(x01_.h, a1_.h, acc[q * 4 + 1]); \
    acc[q * 4 + 2] = DOT2(x01_.h, a2_.h, acc[q * 4 + 2]); \
    acc[q * 4 + 3] = DOT2(x01_.h, a3_.h, acc[q * 4 + 3]); \
    acc[q * 4 + 0] = DOT2(x23_.h, b0_.h, acc[q * 4 + 0]); \
    acc[q * 4 + 1] = DOT2(x23_.h, b1_.h, acc[q * 4 + 1]); \
    acc[q * 4 + 2] = DOT2(x23_.h, b2_.h, acc[q * 4 + 2]); \
    acc[q * 4 + 3] = DOT2(x23_.h, b3_.h, acc[q * 4 + 3]); \
  } }

__global__ __launch_bounds__(512, 2) void k_conv(
    const unsigned int* __restrict__ srcU, unsigned int* __restrict__ dstU,
    const int* __restrict__ off, const unsigned int* __restrict__ pl,
    const unsigned int* __restrict__ Wg, const float* __restrict__ bias) {
  __shared__ unsigned int sW[KVOL * KSTR];   // 62208 B
  __shared__ float sB[CH];

  const int tid = threadIdx.x;
  for (int i = tid; i < KVOL * 512; i += 512) {
    int k = i >> 9, r = i & 511;
    sW[k * KSTR + (r >> 5) * JSTR + (r & 31)] = Wg[i];
  }
  if (tid < CH) sB[tid] = bias[tid];
  __syncthreads();

  const int g = tid >> 3, j = tid & 7;
  const int row = blockIdx.x * 64 + g;
  int beg = 0, ee = 0;
  if (row < N_VOX) { beg = off[row]; ee = off[row + 1]; }

  float acc[CH];
#pragma unroll
  for (int t = 0; t < CH; t++) acc[t] = 0.f;

  int e = beg;
  for (; e + 4 <= ee; e += 4) {
    ENT_LOAD(0, e)
    ENT_LOAD(1, e + 1)
    ENT_LOAD(4, e + 2)
    ENT_LOAD(5, e + 3)
    ENT_DOT(0)
    ENT_DOT(1)
    ENT_DOT(4)
    ENT_DOT(5)
  }
  for (; e + 2 <= ee; e += 2) {
    ENT_LOAD(2, e)
    ENT_LOAD(3, e + 1)
    ENT_DOT(2)
    ENT_DOT(3)
  }
  if (e < ee) {
    ENT_LOAD(6, e)
    ENT_DOT(6)
  }

  // butterfly reduce across the 8 lanes of the group
#pragma unroll
  for (int m = 1; m <= 4; m <<= 1) {
#pragma unroll
    for (int t = 0; t < CH; t++) acc[t] += __shfl_xor(acc[t], m);
  }

  if (row < N_VOX) {
    unsigned int w0 = 0, w1 = 0;
#pragma unroll
    for (int t = 0; t < 16; t++) {
      float lo = fmaxf(acc[2 * t] + sB[2 * t], 0.f);
      float hi = fmaxf(acc[2 * t + 1] + sB[2 * t + 1], 0.f);
      unsigned int pk = pk_f16(lo, hi);
      if ((t >> 1) == j) { if (t & 1) w1 = pk; else w0 = pk; }
    }
    uint2 o = {w0, w1};
    *(uint2*)(dstU + row * 16 + j * 2) = o;
  }
}

// ==================== logits kernel (f16 inputs) ============================
__global__ __launch_bounds__(256) void k_logits(
    const uint4* __restrict__ A4, const uint4* __restrict__ B4,
    const float* __restrict__ Wl, const float* __restrict__ bl,
    float* __restrict__ out) {
  __shared__ float sWl[CH * NCLS];
  __shared__ float sbl[NCLS];
  int tid = threadIdx.x;
  if (tid < CH * NCLS / 4) ((float4*)sWl)[tid] = ((const float4*)Wl)[tid];
  if (tid < NCLS) sbl[tid] = bl[tid];
  __syncthreads();
  int row = blockIdx.x * 256 + tid;
  if (row >= N_VOX) return;
  float acc[NCLS];
#pragma unroll
  for (int jj = 0; jj < NCLS; jj++) acc[jj] = sbl[jj];
#pragma unroll
  for (int q = 0; q < 4; q++) {
    uint4 a = A4[row * 4 + q], b = B4[row * 4 + q];
    unsigned int au[4] = {a.x, a.y, a.z, a.w}, bu[4] = {b.x, b.y, b.z, b.w};
#pragma unroll
    for (int t = 0; t < 4; t++) {
      int c = (q << 3) + (t << 1);
      float x0 = f16_lo(au[t]) + f16_lo(bu[t]);
      float x1 = f16_hi(au[t]) + f16_hi(bu[t]);
#pragma unroll
      for (int jj = 0; jj < NCLS; jj++) {
        acc[jj] = fmaf(x0, sWl[c * NCLS + jj], acc[jj]);
        acc[jj] = fmaf(x1, sWl[(c + 1) * NCLS + jj], acc[jj]);
      }
    }
  }
  float4* op = (float4*)(out + row * NCLS);
#pragma unroll
  for (int j5 = 0; j5 < NCLS / 4; j5++) {
    float4 v = {acc[j5 * 4], acc[j5 * 4 + 1], acc[j5 * 4 + 2], acc[j5 * 4 + 3]};
    op[j5] = v;
  }
}

// ==================== launch ================================================
extern "C" void kernel_launch(void* const* d_in, const int* in_sizes, int n_in,
                              void* d_out, int out_size, void* d_ws, size_t ws_size,
                              hipStream_t stream) {
  const float* in_feats = (const float*)d_in[0];
  const int*   ga       = (const int*)d_in[1];
  const int*   sa       = (const int*)d_in[2];
  const int*   gb       = (const int*)d_in[3];
  const int*   sb       = (const int*)d_in[4];
  const float* w1       = (const float*)d_in[5];
  const float* b1       = (const float*)d_in[6];
  const float* w1_2     = (const float*)d_in[7];
  const float* b1_2     = (const float*)d_in[8];
  const float* w2       = (const float*)d_in[9];
  const float* b2       = (const float*)d_in[10];
  const float* w3       = (const float*)d_in[11];
  const float* b3       = (const float*)d_in[12];
  const float* wl       = (const float*)d_in[13];
  const float* bl       = (const float*)d_in[14];
  float* out = (float*)d_out;

  // ---- workspace carve-up (u32 units, ~88.4 MB) ----
  unsigned int* wsu = (unsigned int*)d_ws;
  size_t o = 0;
  unsigned int* bufA = wsu + o; o += (size_t)MPAD * 16;
  unsigned int* bufB = wsu + o; o += (size_t)MPAD * 16;
  unsigned int* bufC = wsu + o; o += (size_t)MPAD * 16;
  unsigned int* inbf = wsu + o; o += (size_t)MPAD * 16;
  unsigned int* Wg1   = wsu + o; o += WG_U32;
  unsigned int* Wg1_2 = wsu + o; o += WG_U32;
  unsigned int* Wg2   = wsu + o; o += WG_U32;
  unsigned int* Wg3   = wsu + o; o += WG_U32;
  int* off2  = (int*)(wsu + o); o += 2 * MPAD;
  int* ccnt  = (int*)(wsu + o); o += 1024;
  int* cbase = (int*)(wsu + o); o += 1024;
  int* ccur  = (int*)(wsu + o); o += 1024;
  unsigned int* tmp = wsu + o; o += TOT;
  unsigned int* plA = wsu + o; o += TOT;
  unsigned int* plB = wsu + o; o += TOT;

  dim3 blk(256);
  const int g_conv = MPAD / 64;              // 2344 blocks x 512 thr
  const int g_wp   = (WG_U32 + 255) / 256;   // 54
  const int g_bf   = 2344;
  const int g_lg   = (N_VOX + 255) / 256;

  // ---- build row-keyed CSRs via 2-pass counting sort ----
  (void)hipMemsetAsync(ccnt, 0, 1024 * sizeof(int), stream);
  k_c0<<<dim3(NBLK1, 1, 2), dim3(512), 0, stream>>>(sa, sb, ccnt);
  k_cscan<<<2, dim3(512), 0, stream>>>(ccnt, cbase, ccur);
  k_scat<<<NBLK1, dim3(512), 0, stream>>>(sa, ga, ccur, tmp, 0);
  k_p2<<<NCB, dim3(512), 0, stream>>>(tmp, cbase, off2, plA, 0);
  k_scat<<<NBLK1, dim3(512), 0, stream>>>(sb, gb, ccur, tmp, 1);
  k_p2<<<NCB, dim3(512), 0, stream>>>(tmp, cbase, off2, plB, 1);

  // ---- weight prep + activation convert ----
  k_wprep<<<g_wp, blk, 0, stream>>>(w1,   Wg1);
  k_wprep<<<g_wp, blk, 0, stream>>>(w1_2, Wg1_2);
  k_wprep<<<g_wp, blk, 0, stream>>>(w2,   Wg2);
  k_wprep<<<g_wp, blk, 0, stream>>>(w3,   Wg3);
  k_tof16<<<g_bf, blk, 0, stream>>>((const float4*)in_feats, (uint4*)inbf);

  // ---- 4 conv layers (row-parallel, no atomics) ----
  const int* offA = off2;
  const int* offB = off2 + MPAD;
  k_conv<<<g_conv, dim3(512), 0, stream>>>(inbf, bufA, offA, plA, Wg1, b1);
  k_conv<<<g_conv, dim3(512), 0, stream>>>(bufA, bufB, offB, plB, Wg1_2, b1_2);
  k_conv<<<g_conv, dim3(512), 0, stream>>>(inbf, bufC, offB, plB, Wg2, b2);
  k_conv<<<g_conv, dim3(512), 0, stream>>>(bufC, bufA, offA, plA, Wg3, b3);

  // ---- logits ----
  k_logits<<<g_lg, blk, 0, stream>>>((const uint4*)bufB, (const uint4*)bufA,
                                     wl, bl, out);
}